// Round 1
// baseline (2122.484 us; speedup 1.0000x reference)
//
#include <hip/hip_runtime.h>
#include <hip/hip_bf16.h>

#define NTF 600
#define NG  8000
#define DD  256
#define HH  4
#define DKK 32
#define DVV 64
#define DFF 1024

// ---------------- LayerNorm: one 64-thread wave per row of 256 ----------------
__global__ __launch_bounds__(64)
void ln_kernel(const float* __restrict__ x, const float* __restrict__ g,
               const float* __restrict__ b, float* __restrict__ y) {
    int row = blockIdx.x;
    int tid = threadIdx.x;
    const float4* xp = (const float4*)(x + (size_t)row * DD);
    float4 v = xp[tid];
    float s = v.x + v.y + v.z + v.w;
    #pragma unroll
    for (int off = 32; off > 0; off >>= 1) s += __shfl_xor(s, off, 64);
    float mean = s * (1.f / 256.f);
    float dx = v.x - mean, dy = v.y - mean, dz = v.z - mean, dw = v.w - mean;
    float q = dx*dx + dy*dy + dz*dz + dw*dw;
    #pragma unroll
    for (int off = 32; off > 0; off >>= 1) q += __shfl_xor(q, off, 64);
    float inv = rsqrtf(q * (1.f / 256.f) + 1e-5f);
    float4 gg = ((const float4*)g)[tid];
    float4 bb = ((const float4*)b)[tid];
    float4 o;
    o.x = dx * inv * gg.x + bb.x;
    o.y = dy * inv * gg.y + bb.y;
    o.z = dz * inv * gg.z + bb.z;
    o.w = dw * inv * gg.w + bb.w;
    ((float4*)(y + (size_t)row * DD))[tid] = o;
}

// ---------------- gather z[tf_idx] for the 3 channels ----------------
__global__ __launch_bounds__(256)
void gather_kernel(const float* __restrict__ zs, const float* __restrict__ ze,
                   const float* __restrict__ zt, const int* __restrict__ idx,
                   float* __restrict__ os, float* __restrict__ oe, float* __restrict__ ot) {
    int t = blockIdx.x, j = threadIdx.x;
    size_t src = (size_t)idx[t] * DD + j;
    size_t dst = (size_t)t * DD + j;
    os[dst] = zs[src];
    oe[dst] = ze[src];
    ot[dst] = zt[src];
}

// ---------------- generic Y = act(X @ W^T + bias) (+res), W is [N,K] ----------------
// 128x128 tile, BK=16, 256 threads, 8x8 per thread. Requires N%128==0, K%16==0.
template<bool BIAS, bool GELU, bool RES>
__global__ __launch_bounds__(256)
void gemm_xwt(const float* __restrict__ X, const float* __restrict__ W,
              const float* __restrict__ bias, const float* __restrict__ res,
              float* __restrict__ Y, int M, int N, int K) {
    __shared__ float Xs[16][132];
    __shared__ float Ws[16][132];
    const int tid = threadIdx.x;
    const int bm = blockIdx.x * 128, bn = blockIdx.y * 128;
    const int tx = tid & 15, ty = tid >> 4;
    float acc[8][8] = {};
    for (int k0 = 0; k0 < K; k0 += 16) {
        __syncthreads();
        #pragma unroll
        for (int j = 0; j < 8; ++j) {
            int idx = j * 256 + tid;
            int k = idx & 15, m = idx >> 4;
            Xs[k][m] = (bm + m < M) ? X[(size_t)(bm + m) * K + k0 + k] : 0.f;
            Ws[k][m] = W[(size_t)(bn + m) * K + k0 + k];
        }
        __syncthreads();
        #pragma unroll
        for (int k = 0; k < 16; ++k) {
            float4 a0 = *(const float4*)&Xs[k][ty * 8];
            float4 a1 = *(const float4*)&Xs[k][ty * 8 + 4];
            float4 b0 = *(const float4*)&Ws[k][tx * 8];
            float4 b1 = *(const float4*)&Ws[k][tx * 8 + 4];
            float a[8] = {a0.x,a0.y,a0.z,a0.w,a1.x,a1.y,a1.z,a1.w};
            float b[8] = {b0.x,b0.y,b0.z,b0.w,b1.x,b1.y,b1.z,b1.w};
            #pragma unroll
            for (int i = 0; i < 8; ++i)
                #pragma unroll
                for (int j = 0; j < 8; ++j)
                    acc[i][j] += a[i] * b[j];
        }
    }
    #pragma unroll
    for (int i = 0; i < 8; ++i) {
        int m = bm + ty * 8 + i;
        if (m >= M) continue;
        #pragma unroll
        for (int j = 0; j < 8; ++j) {
            int n = bn + tx * 8 + j;
            float v = acc[i][j];
            if (BIAS) v += bias[n];
            if (GELU) v = 0.5f * v * (1.f + erff(v * 0.70710678118654752f));
            if (RES)  v += res[(size_t)m * N + n];
            Y[(size_t)m * N + n] = v;
        }
    }
}

// ---------------- scores + gate + u; writes U and u_mean/alpha_mean ----------------
// block: 32 g-lanes x 4 heads; 8 t per block.
__global__ __launch_bounds__(128)
void scores_kernel(const float* __restrict__ Qse, const float* __restrict__ Qex, const float* __restrict__ Qtx,
                   const float* __restrict__ Kse, const float* __restrict__ Kex, const float* __restrict__ Ktx,
                   const float* __restrict__ gw, const float* __restrict__ gb,
                   float* __restrict__ U, float* __restrict__ umean, float* __restrict__ amean) {
    __shared__ float Qsh[8][3][128];
    __shared__ float red[HH][8][32][4];
    const int gl = threadIdx.x, h = threadIdx.y;
    const int tid = h * 32 + gl;
    const int g = blockIdx.x * 32 + gl;
    const int t0 = blockIdx.y * 8;
    for (int idx = tid; idx < 8 * 3 * 128; idx += 128) {
        int t = idx / 384, r = idx - t * 384;
        int e = r >> 7, dd = r & 127;
        const float* Qp = (e == 0) ? Qse : (e == 1) ? Qex : Qtx;
        Qsh[t][e][dd] = Qp[(size_t)(t0 + t) * 128 + dd];
    }
    float kreg[3][32];
    #pragma unroll
    for (int e = 0; e < 3; ++e) {
        const float* Kp = (e == 0) ? Kse : (e == 1) ? Kex : Ktx;
        const float4* kp4 = (const float4*)(Kp + (size_t)g * 128 + h * DKK);
        #pragma unroll
        for (int d4 = 0; d4 < 8; ++d4) {
            float4 kv = kp4[d4];
            kreg[e][d4*4+0] = kv.x; kreg[e][d4*4+1] = kv.y;
            kreg[e][d4*4+2] = kv.z; kreg[e][d4*4+3] = kv.w;
        }
    }
    float gwr[3][3], gbr[3];
    #pragma unroll
    for (int e = 0; e < 3; ++e)
        #pragma unroll
        for (int f = 0; f < 3; ++f) gwr[e][f] = gw[h * 9 + e * 3 + f];
    #pragma unroll
    for (int f = 0; f < 3; ++f) gbr[f] = gb[h * 3 + f];
    __syncthreads();
    const float sc = 0.17677669529663687f;  // 1/sqrt(32)
    #pragma unroll
    for (int t = 0; t < 8; ++t) {
        float s[3];
        #pragma unroll
        for (int e = 0; e < 3; ++e) {
            const float4* q4 = (const float4*)&Qsh[t][e][h * DKK];
            float acc = 0.f;
            #pragma unroll
            for (int d4 = 0; d4 < 8; ++d4) {
                float4 qv = q4[d4];
                acc += qv.x * kreg[e][d4*4] + qv.y * kreg[e][d4*4+1]
                     + qv.z * kreg[e][d4*4+2] + qv.w * kreg[e][d4*4+3];
            }
            s[e] = acc * sc;
        }
        float lg0 = s[0]*gwr[0][0] + s[1]*gwr[1][0] + s[2]*gwr[2][0] + gbr[0];
        float lg1 = s[0]*gwr[0][1] + s[1]*gwr[1][1] + s[2]*gwr[2][1] + gbr[1];
        float lg2 = s[0]*gwr[0][2] + s[1]*gwr[1][2] + s[2]*gwr[2][2] + gbr[2];
        float mx = fmaxf(lg0, fmaxf(lg1, lg2));
        float e0 = expf(lg0 - mx), e1 = expf(lg1 - mx), e2 = expf(lg2 - mx);
        float inv = 1.f / (e0 + e1 + e2);
        float a0 = e0 * inv, a1 = e1 * inv, a2 = e2 * inv;
        float u = a0*s[0] + a1*s[1] + a2*s[2];
        U[(size_t)(h * NTF + t0 + t) * NG + g] = u;
        red[h][t][gl][0] = u;
        red[h][t][gl][1] = a0;
        red[h][t][gl][2] = a1;
        red[h][t][gl][3] = a2;
    }
    __syncthreads();
    if (h == 0) {
        #pragma unroll
        for (int t = 0; t < 8; ++t) {
            float su = 0.f, s0 = 0.f, s1 = 0.f, s2 = 0.f;
            #pragma unroll
            for (int hh = 0; hh < HH; ++hh) {
                su += red[hh][t][gl][0];
                s0 += red[hh][t][gl][1];
                s1 += red[hh][t][gl][2];
                s2 += red[hh][t][gl][3];
            }
            size_t p = (size_t)(t0 + t) * NG + g;
            umean[p] = su * 0.25f;
            amean[p*3+0] = s0 * 0.25f;
            amean[p*3+1] = s1 * 0.25f;
            amean[p*3+2] = s2 * 0.25f;
        }
    }
}

// ---------------- row softmax over genes, in place (U -> A) ----------------
__global__ __launch_bounds__(256)
void softmax_kernel(float* __restrict__ U) {
    __shared__ float sred[4];
    const int row = blockIdx.x, tid = threadIdx.x;
    float* p = U + (size_t)row * NG;
    float v[32];
    float mx = -1e30f;
    #pragma unroll
    for (int i = 0; i < 32; ++i) {
        int j = i * 256 + tid;
        v[i] = (j < NG) ? p[j] : -1e30f;
        mx = fmaxf(mx, v[i]);
    }
    #pragma unroll
    for (int off = 32; off > 0; off >>= 1) mx = fmaxf(mx, __shfl_xor(mx, off, 64));
    if ((tid & 63) == 0) sred[tid >> 6] = mx;
    __syncthreads();
    mx = fmaxf(fmaxf(sred[0], sred[1]), fmaxf(sred[2], sred[3]));
    float sum = 0.f;
    #pragma unroll
    for (int i = 0; i < 32; ++i) {
        int j = i * 256 + tid;
        v[i] = (j < NG) ? expf(v[i] - mx) : 0.f;
        sum += v[i];
    }
    #pragma unroll
    for (int off = 32; off > 0; off >>= 1) sum += __shfl_xor(sum, off, 64);
    __syncthreads();
    if ((tid & 63) == 0) sred[tid >> 6] = sum;
    __syncthreads();
    float inv = 1.f / (sred[0] + sred[1] + sred[2] + sred[3]);
    #pragma unroll
    for (int i = 0; i < 32; ++i) {
        int j = i * 256 + tid;
        if (j < NG) p[j] = v[i] * inv;
    }
}

// ---------------- A.mean over heads ----------------
__global__ __launch_bounds__(256)
void amean_kernel(const float* __restrict__ A, float* __restrict__ out) {
    size_t idx = (size_t)blockIdx.x * 256 + threadIdx.x;
    const size_t P = (size_t)NTF * NG;
    out[idx] = 0.25f * (A[idx] + A[idx + P] + A[idx + 2*P] + A[idx + 3*P]);
}

// ---------------- out_tf = einsum('htg,ghv->thv') (atomic over g-splits) ----------------
// grid: (75 t-blocks, 4 h, 8 g-splits); 64 threads (one per v)
__global__ __launch_bounds__(64)
void attn_tf_kernel(const float* __restrict__ A, const float* __restrict__ VG,
                    float* __restrict__ AT) {
    __shared__ float As[8][64];
    const int tb = blockIdx.x, h = blockIdx.y, gs = blockIdx.z;
    const int tid = threadIdx.x;
    const int t0 = tb * 8;
    float acc[8] = {};
    const float* Ah = A + (size_t)h * NTF * NG;
    for (int c = 0; c < 16; ++c) {
        int gbase = gs * 1000 + c * 64;
        __syncthreads();
        #pragma unroll
        for (int t = 0; t < 8; ++t)
            As[t][tid] = (c * 64 + tid < 1000) ? Ah[(size_t)(t0 + t) * NG + gbase + tid] : 0.f;
        __syncthreads();
        int lim = min(64, 1000 - c * 64);
        for (int gg = 0; gg < lim; ++gg) {
            float vv = VG[(size_t)(gbase + gg) * DD + h * DVV + tid];
            #pragma unroll
            for (int t = 0; t < 8; ++t) acc[t] += As[t][gg] * vv;
        }
    }
    #pragma unroll
    for (int t = 0; t < 8; ++t)
        atomicAdd(&AT[(size_t)(t0 + t) * DD + h * DVV + tid], acc[t]);
}

// ---------------- out_g = einsum('htg,thv->ghv') ----------------
// grid: (1000 g-blocks of 8, 4 h); 64 threads (one per v)
__global__ __launch_bounds__(64)
void attn_g_kernel(const float* __restrict__ A, const float* __restrict__ VTF,
                   float* __restrict__ AT) {
    __shared__ float As[64][9];
    const int gb = blockIdx.x, h = blockIdx.y, tid = threadIdx.x;
    const int g0 = gb * 8;
    float acc[8] = {};
    const float* Ah = A + (size_t)h * NTF * NG;
    for (int c = 0; c < 10; ++c) {
        int t0 = c * 64;
        __syncthreads();
        if (t0 + tid < NTF) {
            #pragma unroll
            for (int j = 0; j < 8; ++j)
                As[tid][j] = Ah[(size_t)(t0 + tid) * NG + g0 + j];
        } else {
            #pragma unroll
            for (int j = 0; j < 8; ++j) As[tid][j] = 0.f;
        }
        __syncthreads();
        int lim = min(64, NTF - t0);
        for (int tt = 0; tt < lim; ++tt) {
            float vv = VTF[(size_t)(t0 + tt) * DD + h * DVV + tid];
            #pragma unroll
            for (int j = 0; j < 8; ++j) acc[j] += As[tt][j] * vv;
        }
    }
    #pragma unroll
    for (int j = 0; j < 8; ++j)
        AT[(size_t)(g0 + j) * DD + h * DVV + tid] = acc[j];
}

extern "C" void kernel_launch(void* const* d_in, const int* in_sizes, int n_in,
                              void* d_out, int out_size, void* d_ws, size_t ws_size,
                              hipStream_t stream) {
    (void)in_sizes; (void)n_in; (void)out_size; (void)ws_size;
    const float* H_TF   = (const float*)d_in[0];
    const float* H_G    = (const float*)d_in[1];
    const float* z_exp  = (const float*)d_in[2];
    const float* z_seq  = (const float*)d_in[3];
    const float* z_txt  = (const float*)d_in[4];
    const int*   tf_idx = (const int*)d_in[5];
    const float* WQ_seq = (const float*)d_in[6];
    const float* WK_seq = (const float*)d_in[7];
    const float* WQ_exp = (const float*)d_in[8];
    const float* WK_exp = (const float*)d_in[9];
    const float* WQ_txt = (const float*)d_in[10];
    const float* WK_txt = (const float*)d_in[11];
    const float* gate_w = (const float*)d_in[12];
    const float* gate_b = (const float*)d_in[13];
    const float* WVG    = (const float*)d_in[14];
    const float* WVTF   = (const float*)d_in[15];
    const float* WOTF   = (const float*)d_in[16];
    const float* WOG    = (const float*)d_in[17];
    const float* ln_atf_g = (const float*)d_in[18];
    const float* ln_atf_b = (const float*)d_in[19];
    const float* ln_ag_g  = (const float*)d_in[20];
    const float* ln_ag_b  = (const float*)d_in[21];
    const float* ln_ftf_g = (const float*)d_in[22];
    const float* ln_ftf_b = (const float*)d_in[23];
    const float* ln_fg_g  = (const float*)d_in[24];
    const float* ln_fg_b  = (const float*)d_in[25];
    const float* ftf_W1 = (const float*)d_in[26];
    const float* ftf_b1 = (const float*)d_in[27];
    const float* ftf_W2 = (const float*)d_in[28];
    const float* ftf_b2 = (const float*)d_in[29];
    const float* fg_W1  = (const float*)d_in[30];
    const float* fg_b1  = (const float*)d_in[31];
    const float* fg_W2  = (const float*)d_in[32];
    const float* fg_b2  = (const float*)d_in[33];

    float* out = (float*)d_out;
    float* out_HTF3  = out;                    // 600*256
    float* out_HG3   = out + 153600;           // 8000*256
    float* out_Amean = out + 2201600;          // 600*8000
    float* out_umean = out + 7001600;          // 600*8000
    float* out_amean = out + 11801600;         // 600*8000*3

    float* ws = (float*)d_ws;
    float* U      = ws;                        // 4*600*8000 = 19,200,000 (A in place)
    float* G2     = ws;                        // aliases U (dead after attn kernels): 8,192,000
    float* G1     = ws + 8192000;              // 614,400 (also aliases U)
    float* HTFn   = ws + 19200000;             // 153,600  (later reused as LN(H_TF2))
    float* HGn    = HTFn + 153600;             // 2,048,000 (later reused as LN(H_G2))
    float* zt_seq = HGn + 2048000;             // 153,600
    float* zt_exp = zt_seq + 153600;
    float* zt_txt = zt_exp + 153600;
    float* Qse    = zt_txt + 153600;           // 76,800
    float* Qex    = Qse + 76800;
    float* Qtx    = Qex + 76800;
    float* Kse    = Qtx + 76800;               // 1,024,000
    float* Kex    = Kse + 1024000;
    float* Ktx    = Kex + 1024000;
    float* VG     = Ktx + 1024000;             // 2,048,000
    float* VTF    = VG + 2048000;              // 153,600
    float* ATtf   = VTF + 153600;              // 153,600
    float* ATg    = ATtf + 153600;             // 2,048,000
    float* HTF2   = ATg + 2048000;             // 153,600
    float* HG2    = HTF2 + 153600;             // 2,048,000

    // 1) LayerNorms for attention inputs
    ln_kernel<<<NTF, 64, 0, stream>>>(H_TF, ln_atf_g, ln_atf_b, HTFn);
    ln_kernel<<<NG,  64, 0, stream>>>(H_G,  ln_ag_g,  ln_ag_b,  HGn);

    // 2) gather z[tf_idx]
    gather_kernel<<<NTF, 256, 0, stream>>>(z_seq, z_exp, z_txt, tf_idx, zt_seq, zt_exp, zt_txt);

    // 3) projections
    gemm_xwt<false,false,false><<<dim3(5,1),  256, 0, stream>>>(zt_seq, WQ_seq, nullptr, nullptr, Qse, NTF, 128, DD);
    gemm_xwt<false,false,false><<<dim3(5,1),  256, 0, stream>>>(zt_exp, WQ_exp, nullptr, nullptr, Qex, NTF, 128, DD);
    gemm_xwt<false,false,false><<<dim3(5,1),  256, 0, stream>>>(zt_txt, WQ_txt, nullptr, nullptr, Qtx, NTF, 128, DD);
    gemm_xwt<false,false,false><<<dim3(63,1), 256, 0, stream>>>(z_seq,  WK_seq, nullptr, nullptr, Kse, NG,  128, DD);
    gemm_xwt<false,false,false><<<dim3(63,1), 256, 0, stream>>>(z_exp,  WK_exp, nullptr, nullptr, Kex, NG,  128, DD);
    gemm_xwt<false,false,false><<<dim3(63,1), 256, 0, stream>>>(z_txt,  WK_txt, nullptr, nullptr, Ktx, NG,  128, DD);
    gemm_xwt<false,false,false><<<dim3(63,2), 256, 0, stream>>>(HGn,  WVG,  nullptr, nullptr, VG,  NG,  DD, DD);
    gemm_xwt<false,false,false><<<dim3(5,2),  256, 0, stream>>>(HTFn, WVTF, nullptr, nullptr, VTF, NTF, DD, DD);

    // 4) scores + gate + u (+ u_mean, alpha_mean)
    scores_kernel<<<dim3(NG/32, NTF/8), dim3(32,4), 0, stream>>>(
        Qse, Qex, Qtx, Kse, Kex, Ktx, gate_w, gate_b, U, out_umean, out_amean);

    // 5) softmax over genes (in place) + A mean
    softmax_kernel<<<HH*NTF, 256, 0, stream>>>(U);
    amean_kernel<<<(NTF*NG)/256, 256, 0, stream>>>(U, out_Amean);

    // 6) attention contractions
    hipMemsetAsync(ATtf, 0, (size_t)NTF*DD*sizeof(float), stream);
    attn_tf_kernel<<<dim3(NTF/8, HH, 8), 64, 0, stream>>>(U, VG, ATtf);
    attn_g_kernel<<<dim3(NG/8, HH), 64, 0, stream>>>(U, VTF, ATg);

    // 7) output projections + residual
    gemm_xwt<false,false,true><<<dim3(5,2),  256, 0, stream>>>(ATtf, WOTF, nullptr, H_TF, HTF2, NTF, DD, DD);
    gemm_xwt<false,false,true><<<dim3(63,2), 256, 0, stream>>>(ATg,  WOG,  nullptr, H_G,  HG2,  NG,  DD, DD);

    // 8) FFN (TF)
    ln_kernel<<<NTF, 64, 0, stream>>>(HTF2, ln_ftf_g, ln_ftf_b, HTFn);
    gemm_xwt<true,true,false><<<dim3(5,8), 256, 0, stream>>>(HTFn, ftf_W1, ftf_b1, nullptr, G1, NTF, DFF, DD);
    gemm_xwt<true,false,true><<<dim3(5,2), 256, 0, stream>>>(G1, ftf_W2, ftf_b2, HTF2, out_HTF3, NTF, DD, DFF);

    // 9) FFN (genes)
    ln_kernel<<<NG, 64, 0, stream>>>(HG2, ln_fg_g, ln_fg_b, HGn);
    gemm_xwt<true,true,false><<<dim3(63,8), 256, 0, stream>>>(HGn, fg_W1, fg_b1, nullptr, G2, NG, DFF, DD);
    gemm_xwt<true,false,true><<<dim3(63,2), 256, 0, stream>>>(G2, fg_W2, fg_b2, HG2, out_HG3, NG, DD, DFF);
}

// Round 3
// 1650.773 us; speedup vs baseline: 1.2858x; 1.2858x over previous
//
#include <hip/hip_runtime.h>
#include <hip/hip_bf16.h>

#define NTF 600
#define NG  8000
#define DD  256
#define HH  4
#define DKK 32
#define DVV 64
#define DFF 1024

// ---------------- LayerNorm: one 64-thread wave per row of 256 ----------------
__global__ __launch_bounds__(64)
void ln_kernel(const float* __restrict__ x, const float* __restrict__ g,
               const float* __restrict__ b, float* __restrict__ y) {
    int row = blockIdx.x;
    int tid = threadIdx.x;
    const float4* xp = (const float4*)(x + (size_t)row * DD);
    float4 v = xp[tid];
    float s = v.x + v.y + v.z + v.w;
    #pragma unroll
    for (int off = 32; off > 0; off >>= 1) s += __shfl_xor(s, off, 64);
    float mean = s * (1.f / 256.f);
    float dx = v.x - mean, dy = v.y - mean, dz = v.z - mean, dw = v.w - mean;
    float q = dx*dx + dy*dy + dz*dz + dw*dw;
    #pragma unroll
    for (int off = 32; off > 0; off >>= 1) q += __shfl_xor(q, off, 64);
    float inv = rsqrtf(q * (1.f / 256.f) + 1e-5f);
    float4 gg = ((const float4*)g)[tid];
    float4 bb = ((const float4*)b)[tid];
    float4 o;
    o.x = dx * inv * gg.x + bb.x;
    o.y = dy * inv * gg.y + bb.y;
    o.z = dz * inv * gg.z + bb.z;
    o.w = dw * inv * gg.w + bb.w;
    ((float4*)(y + (size_t)row * DD))[tid] = o;
}

// ---------------- gather z[tf_idx] for the 3 channels ----------------
__global__ __launch_bounds__(256)
void gather_kernel(const float* __restrict__ zs, const float* __restrict__ ze,
                   const float* __restrict__ zt, const int* __restrict__ idx,
                   float* __restrict__ os, float* __restrict__ oe, float* __restrict__ ot) {
    int t = blockIdx.x, j = threadIdx.x;
    size_t src = (size_t)idx[t] * DD + j;
    size_t dst = (size_t)t * DD + j;
    os[dst] = zs[src];
    oe[dst] = ze[src];
    ot[dst] = zt[src];
}

// ---------------- shared GEMM core: Y = act(X @ W^T + bias) (+res), W is [N,K] ----------------
// 128x128 tile, BK=16, 256 threads, 8x8 per thread. Requires N%128==0, K%16==0.
template<bool BIAS, bool GELU, bool RES>
__device__ __forceinline__
void gemm_core(const float* __restrict__ X, const float* __restrict__ W,
               const float* __restrict__ bias, const float* __restrict__ res,
               float* __restrict__ Y, int M, int N, int K,
               float Xs[16][132], float Ws[16][132]) {
    const int tid = threadIdx.x;
    const int bm = blockIdx.x * 128, bn = blockIdx.y * 128;
    const int tx = tid & 15, ty = tid >> 4;
    float acc[8][8] = {};
    for (int k0 = 0; k0 < K; k0 += 16) {
        __syncthreads();
        #pragma unroll
        for (int j = 0; j < 8; ++j) {
            int idx = j * 256 + tid;
            int k = idx & 15, m = idx >> 4;
            Xs[k][m] = (bm + m < M) ? X[(size_t)(bm + m) * K + k0 + k] : 0.f;
            Ws[k][m] = W[(size_t)(bn + m) * K + k0 + k];
        }
        __syncthreads();
        #pragma unroll
        for (int k = 0; k < 16; ++k) {
            float4 a0 = *(const float4*)&Xs[k][ty * 8];
            float4 a1 = *(const float4*)&Xs[k][ty * 8 + 4];
            float4 b0 = *(const float4*)&Ws[k][tx * 8];
            float4 b1 = *(const float4*)&Ws[k][tx * 8 + 4];
            float a[8] = {a0.x,a0.y,a0.z,a0.w,a1.x,a1.y,a1.z,a1.w};
            float b[8] = {b0.x,b0.y,b0.z,b0.w,b1.x,b1.y,b1.z,b1.w};
            #pragma unroll
            for (int i = 0; i < 8; ++i)
                #pragma unroll
                for (int j = 0; j < 8; ++j)
                    acc[i][j] += a[i] * b[j];
        }
    }
    #pragma unroll
    for (int i = 0; i < 8; ++i) {
        int m = bm + ty * 8 + i;
        if (m >= M) continue;
        #pragma unroll
        for (int j = 0; j < 8; ++j) {
            int n = bn + tx * 8 + j;
            float v = acc[i][j];
            if (BIAS) v += bias[n];
            if (GELU) v = 0.5f * v * (1.f + erff(v * 0.70710678118654752f));
            if (RES)  v += res[(size_t)m * N + n];
            Y[(size_t)m * N + n] = v;
        }
    }
}

template<bool BIAS, bool GELU, bool RES>
__global__ __launch_bounds__(256)
void gemm_xwt(const float* __restrict__ X, const float* __restrict__ W,
              const float* __restrict__ bias, const float* __restrict__ res,
              float* __restrict__ Y, int M, int N, int K) {
    __shared__ float Xs[16][132];
    __shared__ float Ws[16][132];
    gemm_core<BIAS, GELU, RES>(X, W, bias, res, Y, M, N, K, Xs, Ws);
}

// batched x3 (blockIdx.z selects the problem) — for Q/K projections
__global__ __launch_bounds__(256)
void gemm_xwt3(const float* X0, const float* W0, float* Y0,
               const float* X1, const float* W1, float* Y1,
               const float* X2, const float* W2, float* Y2,
               int M, int N, int K) {
    __shared__ float Xs[16][132];
    __shared__ float Ws[16][132];
    const float* X = (blockIdx.z == 0) ? X0 : (blockIdx.z == 1) ? X1 : X2;
    const float* W = (blockIdx.z == 0) ? W0 : (blockIdx.z == 1) ? W1 : W2;
    float*       Y = (blockIdx.z == 0) ? Y0 : (blockIdx.z == 1) ? Y1 : Y2;
    gemm_core<false, false, false>(X, W, nullptr, nullptr, Y, M, N, K, Xs, Ws);
}

// ---------------- scores + gate + u; writes U and u_mean/alpha_mean ----------------
// block: 32 g-lanes x 4 heads; 8 t per block.
__global__ __launch_bounds__(128)
void scores_kernel(const float* __restrict__ Qse, const float* __restrict__ Qex, const float* __restrict__ Qtx,
                   const float* __restrict__ Kse, const float* __restrict__ Kex, const float* __restrict__ Ktx,
                   const float* __restrict__ gw, const float* __restrict__ gb,
                   float* __restrict__ U, float* __restrict__ umean, float* __restrict__ amean) {
    __shared__ float Qsh[8][3][128];
    __shared__ float red[HH][8][32][4];
    const int gl = threadIdx.x, h = threadIdx.y;
    const int tid = h * 32 + gl;
    const int g = blockIdx.x * 32 + gl;
    const int t0 = blockIdx.y * 8;
    for (int idx = tid; idx < 8 * 3 * 128; idx += 128) {
        int t = idx / 384, r = idx - t * 384;
        int e = r >> 7, dd = r & 127;
        const float* Qp = (e == 0) ? Qse : (e == 1) ? Qex : Qtx;
        Qsh[t][e][dd] = Qp[(size_t)(t0 + t) * 128 + dd];
    }
    float kreg[3][32];
    #pragma unroll
    for (int e = 0; e < 3; ++e) {
        const float* Kp = (e == 0) ? Kse : (e == 1) ? Kex : Ktx;
        const float4* kp4 = (const float4*)(Kp + (size_t)g * 128 + h * DKK);
        #pragma unroll
        for (int d4 = 0; d4 < 8; ++d4) {
            float4 kv = kp4[d4];
            kreg[e][d4*4+0] = kv.x; kreg[e][d4*4+1] = kv.y;
            kreg[e][d4*4+2] = kv.z; kreg[e][d4*4+3] = kv.w;
        }
    }
    float gwr[3][3], gbr[3];
    #pragma unroll
    for (int e = 0; e < 3; ++e)
        #pragma unroll
        for (int f = 0; f < 3; ++f) gwr[e][f] = gw[h * 9 + e * 3 + f];
    #pragma unroll
    for (int f = 0; f < 3; ++f) gbr[f] = gb[h * 3 + f];
    __syncthreads();
    const float sc = 0.17677669529663687f;  // 1/sqrt(32)
    #pragma unroll
    for (int t = 0; t < 8; ++t) {
        float s[3];
        #pragma unroll
        for (int e = 0; e < 3; ++e) {
            const float4* q4 = (const float4*)&Qsh[t][e][h * DKK];
            float acc = 0.f;
            #pragma unroll
            for (int d4 = 0; d4 < 8; ++d4) {
                float4 qv = q4[d4];
                acc += qv.x * kreg[e][d4*4] + qv.y * kreg[e][d4*4+1]
                     + qv.z * kreg[e][d4*4+2] + qv.w * kreg[e][d4*4+3];
            }
            s[e] = acc * sc;
        }
        float lg0 = s[0]*gwr[0][0] + s[1]*gwr[1][0] + s[2]*gwr[2][0] + gbr[0];
        float lg1 = s[0]*gwr[0][1] + s[1]*gwr[1][1] + s[2]*gwr[2][1] + gbr[1];
        float lg2 = s[0]*gwr[0][2] + s[1]*gwr[1][2] + s[2]*gwr[2][2] + gbr[2];
        float mx = fmaxf(lg0, fmaxf(lg1, lg2));
        float e0 = expf(lg0 - mx), e1 = expf(lg1 - mx), e2 = expf(lg2 - mx);
        float inv = 1.f / (e0 + e1 + e2);
        float a0 = e0 * inv, a1 = e1 * inv, a2 = e2 * inv;
        float u = a0*s[0] + a1*s[1] + a2*s[2];
        U[(size_t)(h * NTF + t0 + t) * NG + g] = u;
        red[h][t][gl][0] = u;
        red[h][t][gl][1] = a0;
        red[h][t][gl][2] = a1;
        red[h][t][gl][3] = a2;
    }
    __syncthreads();
    if (h == 0) {
        #pragma unroll
        for (int t = 0; t < 8; ++t) {
            float su = 0.f, s0 = 0.f, s1 = 0.f, s2 = 0.f;
            #pragma unroll
            for (int hh = 0; hh < HH; ++hh) {
                su += red[hh][t][gl][0];
                s0 += red[hh][t][gl][1];
                s1 += red[hh][t][gl][2];
                s2 += red[hh][t][gl][3];
            }
            size_t p = (size_t)(t0 + t) * NG + g;
            umean[p] = su * 0.25f;
            amean[p*3+0] = s0 * 0.25f;
            amean[p*3+1] = s1 * 0.25f;
            amean[p*3+2] = s2 * 0.25f;
        }
    }
}

// ---------------- row softmax over genes (in place, U -> A) fused with A.mean over h ----------------
// one block per t; loops the 4 heads; 512 threads.
__global__ __launch_bounds__(512)
void softmax_amean_kernel(float* __restrict__ U, float* __restrict__ Am) {
    __shared__ float sred[8];
    const int t = blockIdx.x, tid = threadIdx.x;
    const int w = tid >> 6;
    float am[16] = {};
    for (int h = 0; h < HH; ++h) {
        float* p = U + ((size_t)h * NTF + t) * NG;
        float v[16];
        float mx = -1e30f;
        #pragma unroll
        for (int i = 0; i < 16; ++i) {
            int j = i * 512 + tid;
            v[i] = (j < NG) ? p[j] : -1e30f;
            mx = fmaxf(mx, v[i]);
        }
        #pragma unroll
        for (int off = 32; off > 0; off >>= 1) mx = fmaxf(mx, __shfl_xor(mx, off, 64));
        __syncthreads();
        if ((tid & 63) == 0) sred[w] = mx;
        __syncthreads();
        mx = sred[0];
        #pragma unroll
        for (int k = 1; k < 8; ++k) mx = fmaxf(mx, sred[k]);
        float sum = 0.f;
        #pragma unroll
        for (int i = 0; i < 16; ++i) {
            int j = i * 512 + tid;
            v[i] = (j < NG) ? expf(v[i] - mx) : 0.f;
            sum += v[i];
        }
        #pragma unroll
        for (int off = 32; off > 0; off >>= 1) sum += __shfl_xor(sum, off, 64);
        __syncthreads();
        if ((tid & 63) == 0) sred[w] = sum;
        __syncthreads();
        float tot = 0.f;
        #pragma unroll
        for (int k = 0; k < 8; ++k) tot += sred[k];
        float inv = 1.f / tot;
        #pragma unroll
        for (int i = 0; i < 16; ++i) {
            int j = i * 512 + tid;
            float a = v[i] * inv;
            if (j < NG) p[j] = a;
            am[i] += a;
        }
    }
    #pragma unroll
    for (int i = 0; i < 16; ++i) {
        int j = i * 512 + tid;
        if (j < NG) Am[(size_t)t * NG + j] = am[i] * 0.25f;
    }
}

// ---------------- out_tf = einsum('htg,ghv->thv'): per-head GEMM, split-K over g ----------------
// grid (10 t-tiles, 4 h, 16 g-chunks of 512); block 256; 64x64 tile, 4x4/thread; atomic epilogue.
__global__ __launch_bounds__(256)
void attn_tf_kernel(const float* __restrict__ A, const float* __restrict__ VG,
                    float* __restrict__ AT) {
    __shared__ float As[16][68];
    __shared__ float Vs[16][68];
    const int tid = threadIdx.x;
    const int tx = tid & 15, ty = tid >> 4;
    const int m0 = blockIdx.x * 64;
    const int h  = blockIdx.y;
    const int g0 = blockIdx.z * 512;
    const float* Ah = A + (size_t)h * NTF * NG;
    float acc[4][4] = {};
    for (int kk = 0; kk < 512; kk += 16) {
        __syncthreads();
        #pragma unroll
        for (int j = 0; j < 4; ++j) {
            int idx = j * 256 + tid;
            int k = idx & 15, m = idx >> 4;
            int t = m0 + m, g = g0 + kk + k;
            As[k][m] = (t < NTF && g < NG) ? Ah[(size_t)t * NG + g] : 0.f;
            int v = idx & 63, k2 = idx >> 6;
            int g2 = g0 + kk + k2;
            Vs[k2][v] = (g2 < NG) ? VG[(size_t)g2 * DD + h * DVV + v] : 0.f;
        }
        __syncthreads();
        #pragma unroll
        for (int k = 0; k < 16; ++k) {
            float4 a4 = *(const float4*)&As[k][ty * 4];
            float4 b4 = *(const float4*)&Vs[k][tx * 4];
            float a[4] = {a4.x, a4.y, a4.z, a4.w};
            float b[4] = {b4.x, b4.y, b4.z, b4.w};
            #pragma unroll
            for (int i = 0; i < 4; ++i)
                #pragma unroll
                for (int j = 0; j < 4; ++j)
                    acc[i][j] += a[i] * b[j];
        }
    }
    #pragma unroll
    for (int i = 0; i < 4; ++i) {
        int t = m0 + ty * 4 + i;
        if (t >= NTF) continue;
        #pragma unroll
        for (int j = 0; j < 4; ++j)
            atomicAdd(&AT[(size_t)t * DD + h * DVV + tx * 4 + j], acc[i][j]);
    }
}

// ---------------- out_g = einsum('htg,thv->ghv'): per-head GEMM over t ----------------
// grid (125 g-tiles, 4 h); block 256; 64x64 tile, 4x4/thread.
__global__ __launch_bounds__(256)
void attn_g_kernel(const float* __restrict__ A, const float* __restrict__ VTF,
                   float* __restrict__ AT) {
    __shared__ float As[16][68];
    __shared__ float Vs[16][68];
    const int tid = threadIdx.x;
    const int tx = tid & 15, ty = tid >> 4;
    const int g0 = blockIdx.x * 64;
    const int h  = blockIdx.y;
    const float* Ah = A + (size_t)h * NTF * NG;
    float acc[4][4] = {};
    for (int t0 = 0; t0 < NTF; t0 += 16) {
        __syncthreads();
        #pragma unroll
        for (int j = 0; j < 4; ++j) {
            int idx = j * 256 + tid;
            int m = idx & 63, k = idx >> 6;
            int t = t0 + k;
            As[k][m] = (t < NTF) ? Ah[(size_t)t * NG + g0 + m] : 0.f;
            Vs[k][m] = (t < NTF) ? VTF[(size_t)t * DD + h * DVV + m] : 0.f;
        }
        __syncthreads();
        #pragma unroll
        for (int k = 0; k < 16; ++k) {
            float4 a4 = *(const float4*)&As[k][ty * 4];
            float4 b4 = *(const float4*)&Vs[k][tx * 4];
            float a[4] = {a4.x, a4.y, a4.z, a4.w};
            float b[4] = {b4.x, b4.y, b4.z, b4.w};
            #pragma unroll
            for (int i = 0; i < 4; ++i)
                #pragma unroll
                for (int j = 0; j < 4; ++j)
                    acc[i][j] += a[i] * b[j];
        }
    }
    #pragma unroll
    for (int i = 0; i < 4; ++i) {
        float4 o = make_float4(acc[i][0], acc[i][1], acc[i][2], acc[i][3]);
        *(float4*)&AT[(size_t)(g0 + ty * 4 + i) * DD + h * DVV + tx * 4] = o;
    }
}

extern "C" void kernel_launch(void* const* d_in, const int* in_sizes, int n_in,
                              void* d_out, int out_size, void* d_ws, size_t ws_size,
                              hipStream_t stream) {
    (void)in_sizes; (void)n_in; (void)out_size; (void)ws_size;
    const float* H_TF   = (const float*)d_in[0];
    const float* H_G    = (const float*)d_in[1];
    const float* z_exp  = (const float*)d_in[2];
    const float* z_seq  = (const float*)d_in[3];
    const float* z_txt  = (const float*)d_in[4];
    const int*   tf_idx = (const int*)d_in[5];
    const float* WQ_seq = (const float*)d_in[6];
    const float* WK_seq = (const float*)d_in[7];
    const float* WQ_exp = (const float*)d_in[8];
    const float* WK_exp = (const float*)d_in[9];
    const float* WQ_txt = (const float*)d_in[10];
    const float* WK_txt = (const float*)d_in[11];
    const float* gate_w = (const float*)d_in[12];
    const float* gate_b = (const float*)d_in[13];
    const float* WVG    = (const float*)d_in[14];
    const float* WVTF   = (const float*)d_in[15];
    const float* WOTF   = (const float*)d_in[16];
    const float* WOG    = (const float*)d_in[17];
    const float* ln_atf_g = (const float*)d_in[18];
    const float* ln_atf_b = (const float*)d_in[19];
    const float* ln_ag_g  = (const float*)d_in[20];
    const float* ln_ag_b  = (const float*)d_in[21];
    const float* ln_ftf_g = (const float*)d_in[22];
    const float* ln_ftf_b = (const float*)d_in[23];
    const float* ln_fg_g  = (const float*)d_in[24];
    const float* ln_fg_b  = (const float*)d_in[25];
    const float* ftf_W1 = (const float*)d_in[26];
    const float* ftf_b1 = (const float*)d_in[27];
    const float* ftf_W2 = (const float*)d_in[28];
    const float* ftf_b2 = (const float*)d_in[29];
    const float* fg_W1  = (const float*)d_in[30];
    const float* fg_b1  = (const float*)d_in[31];
    const float* fg_W2  = (const float*)d_in[32];
    const float* fg_b2  = (const float*)d_in[33];

    float* out = (float*)d_out;
    float* out_HTF3  = out;                    // 600*256
    float* out_HG3   = out + 153600;           // 8000*256
    float* out_Amean = out + 2201600;          // 600*8000
    float* out_umean = out + 7001600;          // 600*8000
    float* out_amean = out + 11801600;         // 600*8000*3

    float* ws = (float*)d_ws;
    float* U      = ws;                        // 4*600*8000 = 19,200,000 (A in place)
    float* G2     = ws;                        // aliases U (dead after attn kernels): 8,192,000
    float* G1     = ws + 8192000;              // 614,400 (also aliases U)
    float* HTFn   = ws + 19200000;             // 153,600  (later reused as LN(H_TF2))
    float* HGn    = HTFn + 153600;             // 2,048,000 (later reused as LN(H_G2))
    float* zt_seq = HGn + 2048000;             // 153,600
    float* zt_exp = zt_seq + 153600;
    float* zt_txt = zt_exp + 153600;
    float* Qse    = zt_txt + 153600;           // 76,800
    float* Qex    = Qse + 76800;
    float* Qtx    = Qex + 76800;
    float* Kse    = Qtx + 76800;               // 1,024,000
    float* Kex    = Kse + 1024000;
    float* Ktx    = Kex + 1024000;
    float* VG     = Ktx + 1024000;             // 2,048,000
    float* VTF    = VG + 2048000;              // 153,600
    float* ATtf   = VTF + 153600;              // 153,600
    float* ATg    = ATtf + 153600;             // 2,048,000
    float* HTF2   = ATg + 2048000;             // 153,600
    float* HG2    = HTF2 + 153600;             // 2,048,000

    // 1) LayerNorms for attention inputs
    ln_kernel<<<NTF, 64, 0, stream>>>(H_TF, ln_atf_g, ln_atf_b, HTFn);
    ln_kernel<<<NG,  64, 0, stream>>>(H_G,  ln_ag_g,  ln_ag_b,  HGn);

    // 2) gather z[tf_idx]
    gather_kernel<<<NTF, 256, 0, stream>>>(z_seq, z_exp, z_txt, tf_idx, zt_seq, zt_exp, zt_txt);

    // 3) projections (Q's batched, K's batched)
    gemm_xwt3<<<dim3(5, 1, 3),  256, 0, stream>>>(zt_seq, WQ_seq, Qse,
                                                  zt_exp, WQ_exp, Qex,
                                                  zt_txt, WQ_txt, Qtx, NTF, 128, DD);
    gemm_xwt3<<<dim3(63, 1, 3), 256, 0, stream>>>(z_seq, WK_seq, Kse,
                                                  z_exp, WK_exp, Kex,
                                                  z_txt, WK_txt, Ktx, NG, 128, DD);
    gemm_xwt<false,false,false><<<dim3(63,2), 256, 0, stream>>>(HGn,  WVG,  nullptr, nullptr, VG,  NG,  DD, DD);
    gemm_xwt<false,false,false><<<dim3(5,2),  256, 0, stream>>>(HTFn, WVTF, nullptr, nullptr, VTF, NTF, DD, DD);

    // 4) scores + gate + u (+ u_mean, alpha_mean)
    scores_kernel<<<dim3(NG/32, NTF/8), dim3(32,4), 0, stream>>>(
        Qse, Qex, Qtx, Kse, Kex, Ktx, gate_w, gate_b, U, out_umean, out_amean);

    // 5) softmax over genes (in place) fused with A.mean over heads
    softmax_amean_kernel<<<NTF, 512, 0, stream>>>(U, out_Amean);

    // 6) attention contractions (GEMM-shaped)
    hipMemsetAsync(ATtf, 0, (size_t)NTF*DD*sizeof(float), stream);
    attn_tf_kernel<<<dim3(10, HH, 16), 256, 0, stream>>>(U, VG, ATtf);
    attn_g_kernel<<<dim3(NG/64, HH), 256, 0, stream>>>(U, VTF, ATg);

    // 7) output projections + residual
    gemm_xwt<false,false,true><<<dim3(5,2),  256, 0, stream>>>(ATtf, WOTF, nullptr, H_TF, HTF2, NTF, DD, DD);
    gemm_xwt<false,false,true><<<dim3(63,2), 256, 0, stream>>>(ATg,  WOG,  nullptr, H_G,  HG2,  NG,  DD, DD);

    // 8) FFN (TF)
    ln_kernel<<<NTF, 64, 0, stream>>>(HTF2, ln_ftf_g, ln_ftf_b, HTFn);
    gemm_xwt<true,true,false><<<dim3(5,8), 256, 0, stream>>>(HTFn, ftf_W1, ftf_b1, nullptr, G1, NTF, DFF, DD);
    gemm_xwt<true,false,true><<<dim3(5,2), 256, 0, stream>>>(G1, ftf_W2, ftf_b2, HTF2, out_HTF3, NTF, DD, DFF);

    // 9) FFN (genes)
    ln_kernel<<<NG, 64, 0, stream>>>(HG2, ln_fg_g, ln_fg_b, HGn);
    gemm_xwt<true,true,false><<<dim3(63,8), 256, 0, stream>>>(HGn, fg_W1, fg_b1, nullptr, G2, NG, DFF, DD);
    gemm_xwt<true,false,true><<<dim3(63,2), 256, 0, stream>>>(G2, fg_W2, fg_b2, HG2, out_HG3, NG, DD, DFF);
}

// Round 9
// 730.910 us; speedup vs baseline: 2.9039x; 2.2585x over previous
//
#include <hip/hip_runtime.h>
#include <hip/hip_bf16.h>

#define NTF 600
#define NG  8000
#define DD  256
#define HH  4
#define DKK 32
#define DVV 64
#define DFF 1024

typedef __attribute__((ext_vector_type(8))) short frag_ab;   // 8 bf16
typedef __attribute__((ext_vector_type(4))) float frag_cd;   // 4 f32

__device__ __forceinline__ unsigned short f2bu(float f) {
    __hip_bfloat16 h = __float2bfloat16(f);
    return __builtin_bit_cast(unsigned short, h);
}
__device__ __forceinline__ short f2bs(float f) { return (short)f2bu(f); }

// ---------------- f32 -> bf16 convert for z_seq/z_exp/z_txt ----------------
__global__ __launch_bounds__(256)
void cvt3_kernel(const float* __restrict__ a, const float* __restrict__ b, const float* __restrict__ c,
                 unsigned short* __restrict__ oa, unsigned short* __restrict__ ob,
                 unsigned short* __restrict__ oc, int n4) {
    for (int i = blockIdx.x * 256 + threadIdx.x; i < 3 * n4; i += gridDim.x * 256) {
        int sel = i / n4, j = i - sel * n4;
        const float* src = (sel == 0) ? a : (sel == 1) ? b : c;
        unsigned short* dst = (sel == 0) ? oa : (sel == 1) ? ob : oc;
        float4 v = ((const float4*)src)[j];
        ushort4 o = {f2bu(v.x), f2bu(v.y), f2bu(v.z), f2bu(v.w)};
        ((ushort4*)dst)[j] = o;
    }
}

// ---------------- weights f32 -> bf16 (13 tensors, blockIdx.y selects) ----------------
__global__ __launch_bounds__(256)
void cvt_w_kernel(const float* s0, const float* s1, const float* s2, const float* s3,
                  const float* s4, const float* s5, const float* s6, const float* s7,
                  const float* s8, const float* s9, const float* s10, const float* s11,
                  const float* s12, unsigned short* __restrict__ dst) {
    const int y = blockIdx.y;
    const float* src; int off, n;
    switch (y) {
        case 0:  src = s0;  off = 0;       n = 32768;  break;
        case 1:  src = s1;  off = 32768;   n = 32768;  break;
        case 2:  src = s2;  off = 65536;   n = 32768;  break;
        case 3:  src = s3;  off = 98304;   n = 32768;  break;
        case 4:  src = s4;  off = 131072;  n = 32768;  break;
        case 5:  src = s5;  off = 163840;  n = 32768;  break;
        case 6:  src = s6;  off = 196608;  n = 65536;  break;
        case 7:  src = s7;  off = 262144;  n = 65536;  break;
        case 8:  src = s8;  off = 327680;  n = 65536;  break;
        case 9:  src = s9;  off = 393216;  n = 262144; break;
        case 10: src = s10; off = 655360;  n = 262144; break;
        case 11: src = s11; off = 917504;  n = 262144; break;
        default: src = s12; off = 1179648; n = 262144; break;
    }
    const int n4 = n >> 2;
    for (int i = blockIdx.x * 256 + threadIdx.x; i < n4; i += gridDim.x * 256) {
        float4 v = ((const float4*)src)[i];
        ushort4 o = {f2bu(v.x), f2bu(v.y), f2bu(v.z), f2bu(v.w)};
        ((ushort4*)(dst + off))[i] = o;
    }
}

// ---------------- LayerNorm: f32 in, bf16 out ----------------
__global__ __launch_bounds__(64)
void ln_b_kernel(const float* __restrict__ x, const float* __restrict__ g,
                 const float* __restrict__ b, unsigned short* __restrict__ y) {
    int row = blockIdx.x;
    int tid = threadIdx.x;
    const float4* xp = (const float4*)(x + (size_t)row * DD);
    float4 v = xp[tid];
    float s = v.x + v.y + v.z + v.w;
    #pragma unroll
    for (int off = 32; off > 0; off >>= 1) s += __shfl_xor(s, off, 64);
    float mean = s * (1.f / 256.f);
    float dx = v.x - mean, dy = v.y - mean, dz = v.z - mean, dw = v.w - mean;
    float q = dx*dx + dy*dy + dz*dz + dw*dw;
    #pragma unroll
    for (int off = 32; off > 0; off >>= 1) q += __shfl_xor(q, off, 64);
    float inv = rsqrtf(q * (1.f / 256.f) + 1e-5f);
    float4 gg = ((const float4*)g)[tid];
    float4 bb = ((const float4*)b)[tid];
    ushort4 o = {f2bu(dx * inv * gg.x + bb.x), f2bu(dy * inv * gg.y + bb.y),
                 f2bu(dz * inv * gg.z + bb.z), f2bu(dw * inv * gg.w + bb.w)};
    ((ushort4*)(y + (size_t)row * DD))[tid] = o;
}

// ---------------- gather z[tf_idx] -> bf16 ----------------
__global__ __launch_bounds__(256)
void gather_b_kernel(const float* __restrict__ zs, const float* __restrict__ ze,
                     const float* __restrict__ zt, const int* __restrict__ idx,
                     unsigned short* __restrict__ os, unsigned short* __restrict__ oe,
                     unsigned short* __restrict__ ot) {
    int t = blockIdx.x, j = threadIdx.x;
    size_t src = (size_t)idx[t] * DD + j;
    size_t dst = (size_t)t * DD + j;
    os[dst] = f2bu(zs[src]);
    oe[dst] = f2bu(ze[src]);
    ot[dst] = f2bu(zt[src]);
}

// ---------------- MFMA GEMM: Y = act(X @ W^T + bias) (+res) ----------------
// X: [M,K] bf16 (or f32 if XF32), W: [N,K] bf16, res/bias f32, Y f32 or bf16.
// Block 256 thr = 4 waves (2x2); tile 64x128; K-step 32. Requires N%128==0, K%32==0.
template<bool XF32, bool BIAS, bool GELU, bool RES, bool OB16>
__device__ __forceinline__
void mgemm_core(const void* __restrict__ Xv, const unsigned short* __restrict__ W,
                const float* __restrict__ bias, const float* __restrict__ res,
                void* __restrict__ Yv, int M, int N, int K) {
    const int lane = threadIdx.x & 63, wv = threadIdx.x >> 6;
    const int wm = wv >> 1, wn = wv & 1;
    const int lr = lane & 15, lk = lane >> 4;
    const int m0 = blockIdx.x * 64, n0 = blockIdx.y * 128;
    frag_cd zz = {0.f, 0.f, 0.f, 0.f};
    frag_cd acc[2][4];
    #pragma unroll
    for (int mi = 0; mi < 2; ++mi)
        #pragma unroll
        for (int ni = 0; ni < 4; ++ni) acc[mi][ni] = zz;
    int arow[2], brow[4];
    #pragma unroll
    for (int mi = 0; mi < 2; ++mi) arow[mi] = min(m0 + wm * 32 + mi * 16 + lr, M - 1);
    #pragma unroll
    for (int ni = 0; ni < 4; ++ni) brow[ni] = n0 + wn * 64 + ni * 16 + lr;
    for (int k0 = 0; k0 < K; k0 += 32) {
        frag_ab af[2], bfr[4];
        #pragma unroll
        for (int mi = 0; mi < 2; ++mi) {
            if (XF32) {
                const float* xp = (const float*)Xv + (size_t)arow[mi] * K + k0 + lk * 8;
                float4 v0 = *(const float4*)xp;
                float4 v1 = *(const float4*)(xp + 4);
                frag_ab t;
                t[0] = f2bs(v0.x); t[1] = f2bs(v0.y); t[2] = f2bs(v0.z); t[3] = f2bs(v0.w);
                t[4] = f2bs(v1.x); t[5] = f2bs(v1.y); t[6] = f2bs(v1.z); t[7] = f2bs(v1.w);
                af[mi] = t;
            } else {
                af[mi] = *(const frag_ab*)((const unsigned short*)Xv + (size_t)arow[mi] * K + k0 + lk * 8);
            }
        }
        #pragma unroll
        for (int ni = 0; ni < 4; ++ni)
            bfr[ni] = *(const frag_ab*)(W + (size_t)brow[ni] * K + k0 + lk * 8);
        #pragma unroll
        for (int mi = 0; mi < 2; ++mi)
            #pragma unroll
            for (int ni = 0; ni < 4; ++ni)
                acc[mi][ni] = __builtin_amdgcn_mfma_f32_16x16x32_bf16(af[mi], bfr[ni], acc[mi][ni], 0, 0, 0);
    }
    #pragma unroll
    for (int ni = 0; ni < 4; ++ni) {
        const int n = brow[ni];
        const float bn = BIAS ? bias[n] : 0.f;
        #pragma unroll
        for (int mi = 0; mi < 2; ++mi) {
            #pragma unroll
            for (int r = 0; r < 4; ++r) {
                const int m = m0 + wm * 32 + mi * 16 + lk * 4 + r;
                if (m < M) {
                    float v = acc[mi][ni][r] + bn;
                    if (GELU) v = 0.5f * v * (1.f + erff(v * 0.70710678118654752f));
                    if (RES)  v += res[(size_t)m * N + n];
                    if (OB16) ((unsigned short*)Yv)[(size_t)m * N + n] = f2bu(v);
                    else      ((float*)Yv)[(size_t)m * N + n] = v;
                }
            }
        }
    }
}

template<bool XF32, bool BIAS, bool GELU, bool RES, bool OB16>
__global__ __launch_bounds__(256)
void mgemm_kernel(const void* __restrict__ X, const unsigned short* __restrict__ W,
                  const float* __restrict__ bias, const float* __restrict__ res,
                  void* __restrict__ Y, int M, int N, int K) {
    mgemm_core<XF32, BIAS, GELU, RES, OB16>(X, W, bias, res, Y, M, N, K);
}

// 3 problems batched via blockIdx.z (Q/K projections), bf16 out
__global__ __launch_bounds__(256)
void mgemm3_kernel(const unsigned short* X0, const unsigned short* W0, unsigned short* Y0,
                   const unsigned short* X1, const unsigned short* W1, unsigned short* Y1,
                   const unsigned short* X2, const unsigned short* W2, unsigned short* Y2,
                   int M, int N, int K) {
    const unsigned short* X = (blockIdx.z == 0) ? X0 : (blockIdx.z == 1) ? X1 : X2;
    const unsigned short* W = (blockIdx.z == 0) ? W0 : (blockIdx.z == 1) ? W1 : W2;
    unsigned short*       Y = (blockIdx.z == 0) ? Y0 : (blockIdx.z == 1) ? Y1 : Y2;
    mgemm_core<false, false, false, false, true>(X, W, nullptr, nullptr, Y, M, N, K);
}

// ---------------- scores + gate + u via MFMA; writes U, umean, alpha_mean ----------------
// Block 256 = 4 waves; wave w owns rows [t0+w*16, +16) x 64 g, ALL 4 heads (reduced in regs).
__global__ __launch_bounds__(256)
void scores_mfma(const unsigned short* __restrict__ Qse, const unsigned short* __restrict__ Qex,
                 const unsigned short* __restrict__ Qtx,
                 const unsigned short* __restrict__ Kse, const unsigned short* __restrict__ Kex,
                 const unsigned short* __restrict__ Ktx,
                 const float* __restrict__ gw, const float* __restrict__ gb,
                 float* __restrict__ U, float* __restrict__ umean, float* __restrict__ amean) {
    const int lane = threadIdx.x & 63, wv = threadIdx.x >> 6;
    const int lr = lane & 15, lk = lane >> 4;
    const int t0 = blockIdx.x * 64 + wv * 16;
    const int g0 = blockIdx.y * 64;
    const int tq = min(t0 + lr, NTF - 1);
    frag_cd zz = {0.f, 0.f, 0.f, 0.f};

    frag_ab qf[3][4];
    #pragma unroll
    for (int h = 0; h < HH; ++h) {
        qf[0][h] = *(const frag_ab*)(Qse + (size_t)tq * 128 + h * DKK + lk * 8);
        qf[1][h] = *(const frag_ab*)(Qex + (size_t)tq * 128 + h * DKK + lk * 8);
        qf[2][h] = *(const frag_ab*)(Qtx + (size_t)tq * 128 + h * DKK + lk * 8);
    }
    float gwr[HH][3][3], gbr[HH][3];
    #pragma unroll
    for (int h = 0; h < HH; ++h) {
        #pragma unroll
        for (int e = 0; e < 3; ++e)
            #pragma unroll
            for (int f = 0; f < 3; ++f) gwr[h][e][f] = gw[h * 9 + e * 3 + f];
        #pragma unroll
        for (int f = 0; f < 3; ++f) gbr[h][f] = gb[h * 3 + f];
    }
    const float sc = 0.17677669529663687f;  // 1/sqrt(32)

    #pragma unroll
    for (int gi = 0; gi < 4; ++gi) {
        const int gg = g0 + gi * 16;
        const int gk = gg + lr;
        float us[4] = {0.f, 0.f, 0.f, 0.f};
        float a0s[4] = {0.f, 0.f, 0.f, 0.f};
        float a1s[4] = {0.f, 0.f, 0.f, 0.f};
        float a2s[4] = {0.f, 0.f, 0.f, 0.f};
        #pragma unroll
        for (int h = 0; h < HH; ++h) {
            frag_ab kf0 = *(const frag_ab*)(Kse + (size_t)gk * 128 + h * DKK + lk * 8);
            frag_ab kf1 = *(const frag_ab*)(Kex + (size_t)gk * 128 + h * DKK + lk * 8);
            frag_ab kf2 = *(const frag_ab*)(Ktx + (size_t)gk * 128 + h * DKK + lk * 8);
            frag_cd s0 = __builtin_amdgcn_mfma_f32_16x16x32_bf16(qf[0][h], kf0, zz, 0, 0, 0);
            frag_cd s1 = __builtin_amdgcn_mfma_f32_16x16x32_bf16(qf[1][h], kf1, zz, 0, 0, 0);
            frag_cd s2 = __builtin_amdgcn_mfma_f32_16x16x32_bf16(qf[2][h], kf2, zz, 0, 0, 0);
            #pragma unroll
            for (int r = 0; r < 4; ++r) {
                const int t = t0 + lk * 4 + r;
                float e0 = s0[r] * sc, e1 = s1[r] * sc, e2 = s2[r] * sc;
                float lg0 = e0 * gwr[h][0][0] + e1 * gwr[h][1][0] + e2 * gwr[h][2][0] + gbr[h][0];
                float lg1 = e0 * gwr[h][0][1] + e1 * gwr[h][1][1] + e2 * gwr[h][2][1] + gbr[h][1];
                float lg2 = e0 * gwr[h][0][2] + e1 * gwr[h][1][2] + e2 * gwr[h][2][2] + gbr[h][2];
                float mx = fmaxf(lg0, fmaxf(lg1, lg2));
                float x0 = __expf(lg0 - mx), x1 = __expf(lg1 - mx), x2 = __expf(lg2 - mx);
                float inv = 1.f / (x0 + x1 + x2);
                float a0 = x0 * inv, a1 = x1 * inv, a2 = x2 * inv;
                float u = a0 * e0 + a1 * e1 + a2 * e2;
                if (t < NTF) U[((size_t)h * NTF + t) * NG + gg + lr] = u;
                us[r] += u; a0s[r] += a0; a1s[r] += a1; a2s[r] += a2;
            }
        }
        #pragma unroll
        for (int r = 0; r < 4; ++r) {
            const int t = t0 + lk * 4 + r;
            if (t < NTF) {
                size_t p = (size_t)t * NG + gg + lr;
                umean[p] = us[r] * 0.25f;
                amean[p * 3 + 0] = a0s[r] * 0.25f;
                amean[p * 3 + 1] = a1s[r] * 0.25f;
                amean[p * 3 + 2] = a2s[r] * 0.25f;
            }
        }
    }
}

// ---------------- row softmax over genes (in place, U -> A) fused with A.mean over h ----------------
__global__ __launch_bounds__(512)
void softmax_amean_kernel(float* __restrict__ U, float* __restrict__ Am) {
    __shared__ float sred[8];
    const int t = blockIdx.x, tid = threadIdx.x;
    const int w = tid >> 6;
    float am[16] = {};
    for (int h = 0; h < HH; ++h) {
        float* p = U + ((size_t)h * NTF + t) * NG;
        float v[16];
        float mx = -1e30f;
        #pragma unroll
        for (int i = 0; i < 16; ++i) {
            int j = i * 512 + tid;
            v[i] = (j < NG) ? p[j] : -1e30f;
            mx = fmaxf(mx, v[i]);
        }
        #pragma unroll
        for (int off = 32; off > 0; off >>= 1) mx = fmaxf(mx, __shfl_xor(mx, off, 64));
        __syncthreads();
        if ((tid & 63) == 0) sred[w] = mx;
        __syncthreads();
        mx = sred[0];
        #pragma unroll
        for (int k = 1; k < 8; ++k) mx = fmaxf(mx, sred[k]);
        float sum = 0.f;
        #pragma unroll
        for (int i = 0; i < 16; ++i) {
            int j = i * 512 + tid;
            v[i] = (j < NG) ? __expf(v[i] - mx) : 0.f;
            sum += v[i];
        }
        #pragma unroll
        for (int off = 32; off > 0; off >>= 1) sum += __shfl_xor(sum, off, 64);
        __syncthreads();
        if ((tid & 63) == 0) sred[w] = sum;
        __syncthreads();
        float tot = 0.f;
        #pragma unroll
        for (int k = 0; k < 8; ++k) tot += sred[k];
        float inv = 1.f / tot;
        #pragma unroll
        for (int i = 0; i < 16; ++i) {
            int j = i * 512 + tid;
            float a = v[i] * inv;
            if (j < NG) p[j] = a;
            am[i] += a;
        }
    }
    #pragma unroll
    for (int i = 0; i < 16; ++i) {
        int j = i * 512 + tid;
        if (j < NG) Am[(size_t)t * NG + j] = am[i] * 0.25f;
    }
}

// ---------------- out_tf = einsum('htg,ghv->thv'): split-K over g, atomic epilogue ----------------
__global__ __launch_bounds__(256)
void attn_tf_kernel(const float* __restrict__ A, const float* __restrict__ VG,
                    float* __restrict__ AT) {
    __shared__ float As[16][68];
    __shared__ float Vs[16][68];
    const int tid = threadIdx.x;
    const int tx = tid & 15, ty = tid >> 4;
    const int m0 = blockIdx.x * 64;
    const int h  = blockIdx.y;
    const int g0 = blockIdx.z * 512;
    const float* Ah = A + (size_t)h * NTF * NG;
    float acc[4][4] = {};
    for (int kk = 0; kk < 512; kk += 16) {
        __syncthreads();
        #pragma unroll
        for (int j = 0; j < 4; ++j) {
            int idx = j * 256 + tid;
            int k = idx & 15, m = idx >> 4;
            int t = m0 + m, g = g0 + kk + k;
            // g < NG guard is REQUIRED: 16 chunks x 512 = 8192 > NG=8000.
            As[k][m] = (t < NTF && g < NG) ? Ah[(size_t)t * NG + g] : 0.f;
            int v = idx & 63, k2 = idx >> 6;
            int g2 = g0 + kk + k2;
            Vs[k2][v] = (g2 < NG) ? VG[(size_t)g2 * DD + h * DVV + v] : 0.f;
        }
        __syncthreads();
        #pragma unroll
        for (int k = 0; k < 16; ++k) {
            float4 a4 = *(const float4*)&As[k][ty * 4];
            float4 b4 = *(const float4*)&Vs[k][tx * 4];
            float a[4] = {a4.x, a4.y, a4.z, a4.w};
            float b[4] = {b4.x, b4.y, b4.z, b4.w};
            #pragma unroll
            for (int i = 0; i < 4; ++i)
                #pragma unroll
                for (int j = 0; j < 4; ++j)
                    acc[i][j] += a[i] * b[j];
        }
    }
    #pragma unroll
    for (int i = 0; i < 4; ++i) {
        int t = m0 + ty * 4 + i;
        if (t >= NTF) continue;
        #pragma unroll
        for (int j = 0; j < 4; ++j)
            atomicAdd(&AT[(size_t)t * DD + h * DVV + tx * 4 + j], acc[i][j]);
    }
}

// ---------------- out_g = einsum('htg,thv->ghv'), bf16 output ----------------
__global__ __launch_bounds__(256)
void attn_g_kernel(const float* __restrict__ A, const float* __restrict__ VTF,
                   unsigned short* __restrict__ ATb) {
    __shared__ float As[16][68];
    __shared__ float Vs[16][68];
    const int tid = threadIdx.x;
    const int tx = tid & 15, ty = tid >> 4;
    const int g0 = blockIdx.x * 64;
    const int h  = blockIdx.y;
    const float* Ah = A + (size_t)h * NTF * NG;
    float acc[4][4] = {};
    for (int t0 = 0; t0 < NTF; t0 += 16) {
        __syncthreads();
        #pragma unroll
        for (int j = 0; j < 4; ++j) {
            int idx = j * 256 + tid;
            int m = idx & 63, k = idx >> 6;
            int t = t0 + k;
            As[k][m] = (t < NTF) ? Ah[(size_t)t * NG + g0 + m] : 0.f;
            Vs[k][m] = (t < NTF) ? VTF[(size_t)t * DD + h * DVV + m] : 0.f;
        }
        __syncthreads();
        #pragma unroll
        for (int k = 0; k < 16; ++k) {
            float4 a4 = *(const float4*)&As[k][ty * 4];
            float4 b4 = *(const float4*)&Vs[k][tx * 4];
            float a[4] = {a4.x, a4.y, a4.z, a4.w};
            float b[4] = {b4.x, b4.y, b4.z, b4.w};
            #pragma unroll
            for (int i = 0; i < 4; ++i)
                #pragma unroll
                for (int j = 0; j < 4; ++j)
                    acc[i][j] += a[i] * b[j];
        }
    }
    #pragma unroll
    for (int i = 0; i < 4; ++i) {
        ushort4 o = {f2bu(acc[i][0]), f2bu(acc[i][1]), f2bu(acc[i][2]), f2bu(acc[i][3])};
        *(ushort4*)&ATb[(size_t)(g0 + ty * 4 + i) * DD + h * DVV + tx * 4] = o;
    }
}

// ---------------- f32 SIMT GEMM (kept only for WOTF: X=ATtf f32 from atomics) ----------------
template<bool RES>
__global__ __launch_bounds__(256)
void gemm_xwt(const float* __restrict__ X, const float* __restrict__ W,
              const float* __restrict__ res, float* __restrict__ Y, int M, int N, int K) {
    __shared__ float Xs[16][132];
    __shared__ float Ws[16][132];
    const int tid = threadIdx.x;
    const int bm = blockIdx.x * 128, bn = blockIdx.y * 128;
    const int tx = tid & 15, ty = tid >> 4;
    float acc[8][8] = {};
    for (int k0 = 0; k0 < K; k0 += 16) {
        __syncthreads();
        #pragma unroll
        for (int j = 0; j < 8; ++j) {
            int idx = j * 256 + tid;
            int k = idx & 15, m = idx >> 4;
            Xs[k][m] = (bm + m < M) ? X[(size_t)(bm + m) * K + k0 + k] : 0.f;
            Ws[k][m] = W[(size_t)(bn + m) * K + k0 + k];
        }
        __syncthreads();
        #pragma unroll
        for (int k = 0; k < 16; ++k) {
            float4 a0 = *(const float4*)&Xs[k][ty * 8];
            float4 a1 = *(const float4*)&Xs[k][ty * 8 + 4];
            float4 b0 = *(const float4*)&Ws[k][tx * 8];
            float4 b1 = *(const float4*)&Ws[k][tx * 8 + 4];
            float a[8] = {a0.x,a0.y,a0.z,a0.w,a1.x,a1.y,a1.z,a1.w};
            float b[8] = {b0.x,b0.y,b0.z,b0.w,b1.x,b1.y,b1.z,b1.w};
            #pragma unroll
            for (int i = 0; i < 8; ++i)
                #pragma unroll
                for (int j = 0; j < 8; ++j)
                    acc[i][j] += a[i] * b[j];
        }
    }
    #pragma unroll
    for (int i = 0; i < 8; ++i) {
        int m = bm + ty * 8 + i;
        if (m >= M) continue;
        #pragma unroll
        for (int j = 0; j < 8; ++j) {
            int n = bn + tx * 8 + j;
            float v = acc[i][j];
            if (RES) v += res[(size_t)m * N + n];
            Y[(size_t)m * N + n] = v;
        }
    }
}

extern "C" void kernel_launch(void* const* d_in, const int* in_sizes, int n_in,
                              void* d_out, int out_size, void* d_ws, size_t ws_size,
                              hipStream_t stream) {
    (void)in_sizes; (void)n_in; (void)out_size; (void)ws_size;
    const float* H_TF   = (const float*)d_in[0];
    const float* H_G    = (const float*)d_in[1];
    const float* z_exp  = (const float*)d_in[2];
    const float* z_seq  = (const float*)d_in[3];
    const float* z_txt  = (const float*)d_in[4];
    const int*   tf_idx = (const int*)d_in[5];
    const float* WQ_seq = (const float*)d_in[6];
    const float* WK_seq = (const float*)d_in[7];
    const float* WQ_exp = (const float*)d_in[8];
    const float* WK_exp = (const float*)d_in[9];
    const float* WQ_txt = (const float*)d_in[10];
    const float* WK_txt = (const float*)d_in[11];
    const float* gate_w = (const float*)d_in[12];
    const float* gate_b = (const float*)d_in[13];
    const float* WVG    = (const float*)d_in[14];
    const float* WVTF   = (const float*)d_in[15];
    const float* WOTF   = (const float*)d_in[16];
    const float* WOG    = (const float*)d_in[17];
    const float* ln_atf_g = (const float*)d_in[18];
    const float* ln_atf_b = (const float*)d_in[19];
    const float* ln_ag_g  = (const float*)d_in[20];
    const float* ln_ag_b  = (const float*)d_in[21];
    const float* ln_ftf_g = (const float*)d_in[22];
    const float* ln_ftf_b = (const float*)d_in[23];
    const float* ln_fg_g  = (const float*)d_in[24];
    const float* ln_fg_b  = (const float*)d_in[25];
    const float* ftf_W1 = (const float*)d_in[26];
    const float* ftf_b1 = (const float*)d_in[27];
    const float* ftf_W2 = (const float*)d_in[28];
    const float* ftf_b2 = (const float*)d_in[29];
    const float* fg_W1  = (const float*)d_in[30];
    const float* fg_b1  = (const float*)d_in[31];
    const float* fg_W2  = (const float*)d_in[32];
    const float* fg_b2  = (const float*)d_in[33];

    float* out = (float*)d_out;
    float* out_HTF3  = out;                    // 600*256
    float* out_HG3   = out + 153600;           // 8000*256
    float* out_Amean = out + 2201600;          // 600*8000
    float* out_umean = out + 7001600;          // 600*8000
    float* out_amean = out + 11801600;         // 600*8000*3

    // ---- workspace layout (f32 units) ----
    float* ws = (float*)d_ws;
    float* U    = ws;                          // 19,200,000 f32  (A in place after softmax)
    float* VG   = ws + 19200000;               //  2,048,000
    float* VTF  = VG + 2048000;                //    153,600
    float* ATtf = VTF + 153600;                //    153,600
    float* HTF2 = ATtf + 153600;               //    153,600
    float* HG2  = HTF2 + 153600;               //  2,048,000  -> f32 end 23,756,800
    // f32 aliases inside U (A dead after attn kernels):
    float* G2 = U;                             // 8,192,000 (fg gelu out)
    float* G1 = U + 8192000;                   //   614,400 (ftf gelu out)
    // bf16 region (dedicated)
    unsigned short* bws   = (unsigned short*)(ws + 23756800);
    unsigned short* Kb_se = bws;               // 1,024,000 each
    unsigned short* Kb_ex = bws + 1024000;
    unsigned short* Kb_tx = bws + 2048000;
    unsigned short* Qb_se = bws + 3072000;     // 76,800 each
    unsigned short* Qb_ex = bws + 3148800;
    unsigned short* Qb_tx = bws + 3225600;
    unsigned short* Wb    = bws + 3302400;     // 1,441,792
    unsigned short* HTFnb = bws + 4744192;     // 153,600  (attn LN, reused for FFN LN)
    unsigned short* HGnb  = bws + 4897792;     // 2,048,000 -> bf16 end 6,945,792
    // bf16 aliases inside U (dead before scores writes U):
    unsigned short* zb_se = (unsigned short*)U;             // 2,048,000 each
    unsigned short* zb_ex = zb_se + 2048000;
    unsigned short* zb_tx = zb_se + 4096000;
    unsigned short* ztb_se = zb_se + 6144000;               // 153,600 each
    unsigned short* ztb_ex = ztb_se + 153600;
    unsigned short* ztb_tx = ztb_se + 307200;
    // bf16 alias inside VG (dead after attn_tf):
    unsigned short* ATgb = (unsigned short*)VG;             // 2,048,000

    // weight bf16 offsets inside Wb (order matches cvt_w_kernel)
    unsigned short* WQse_b = Wb + 0;
    unsigned short* WQex_b = Wb + 32768;
    unsigned short* WQtx_b = Wb + 65536;
    unsigned short* WKse_b = Wb + 98304;
    unsigned short* WKex_b = Wb + 131072;
    unsigned short* WKtx_b = Wb + 163840;
    unsigned short* WVGb   = Wb + 196608;
    unsigned short* WVTFb  = Wb + 262144;
    unsigned short* WOGb   = Wb + 327680;
    unsigned short* ftfW1b = Wb + 393216;
    unsigned short* ftfW2b = Wb + 655360;
    unsigned short* fgW1b  = Wb + 917504;
    unsigned short* fgW2b  = Wb + 1179648;

    // 0) converts
    cvt3_kernel<<<750, 256, 0, stream>>>(z_seq, z_exp, z_txt, zb_se, zb_ex, zb_tx, 512000);
    cvt_w_kernel<<<dim3(64, 13), 256, 0, stream>>>(
        WQ_seq, WQ_exp, WQ_txt, WK_seq, WK_exp, WK_txt,
        WVG, WVTF, WOG, ftf_W1, ftf_W2, fg_W1, fg_W2, Wb);

    // 1) attention layernorms (bf16 out)
    ln_b_kernel<<<NTF, 64, 0, stream>>>(H_TF, ln_atf_g, ln_atf_b, HTFnb);
    ln_b_kernel<<<NG,  64, 0, stream>>>(H_G,  ln_ag_g,  ln_ag_b,  HGnb);

    // 2) gather z[tf_idx] (bf16 out)
    gather_b_kernel<<<NTF, 256, 0, stream>>>(z_seq, z_exp, z_txt, tf_idx, ztb_se, ztb_ex, ztb_tx);

    // 3) projections (MFMA)
    mgemm3_kernel<<<dim3(10, 1, 3), 256, 0, stream>>>(ztb_se, WQse_b, Qb_se,
                                                      ztb_ex, WQex_b, Qb_ex,
                                                      ztb_tx, WQtx_b, Qb_tx, NTF, 128, DD);
    mgemm3_kernel<<<dim3(125, 1, 3), 256, 0, stream>>>(zb_se, WKse_b, Kb_se,
                                                       zb_ex, WKex_b, Kb_ex,
                                                       zb_tx, WKtx_b, Kb_tx, NG, 128, DD);
    mgemm_kernel<false,false,false,false,false><<<dim3(125, 2), 256, 0, stream>>>(
        HGnb, WVGb, nullptr, nullptr, VG, NG, DD, DD);
    mgemm_kernel<false,false,false,false,false><<<dim3(10, 2), 256, 0, stream>>>(
        HTFnb, WVTFb, nullptr, nullptr, VTF, NTF, DD, DD);

    // 4) scores + gate + u (+ umean, alpha_mean) — MFMA
    scores_mfma<<<dim3(10, 125), 256, 0, stream>>>(
        Qb_se, Qb_ex, Qb_tx, Kb_se, Kb_ex, Kb_tx, gate_w, gate_b, U, out_umean, out_amean);

    // 5) softmax over genes (in place) fused with A.mean over heads
    softmax_amean_kernel<<<NTF, 512, 0, stream>>>(U, out_Amean);

    // 6) attention contractions
    hipMemsetAsync(ATtf, 0, (size_t)NTF * DD * sizeof(float), stream);
    attn_tf_kernel<<<dim3(10, HH, 16), 256, 0, stream>>>(U, VG, ATtf);
    attn_g_kernel<<<dim3(NG / 64, HH), 256, 0, stream>>>(U, VTF, ATgb);

    // 7) output projections + residual
    gemm_xwt<true><<<dim3(5, 2), 256, 0, stream>>>(ATtf, WOTF, H_TF, HTF2, NTF, DD, DD);
    mgemm_kernel<false,false,false,true,false><<<dim3(125, 2), 256, 0, stream>>>(
        ATgb, WOGb, nullptr, H_G, HG2, NG, DD, DD);

    // 8) FFN (TF)
    ln_b_kernel<<<NTF, 64, 0, stream>>>(HTF2, ln_ftf_g, ln_ftf_b, HTFnb);
    mgemm_kernel<false,true,true,false,false><<<dim3(10, 8), 256, 0, stream>>>(
        HTFnb, ftfW1b, ftf_b1, nullptr, G1, NTF, DFF, DD);
    mgemm_kernel<true,true,false,true,false><<<dim3(10, 2), 256, 0, stream>>>(
        G1, ftfW2b, ftf_b2, HTF2, out_HTF3, NTF, DD, DFF);

    // 9) FFN (genes)
    ln_b_kernel<<<NG, 64, 0, stream>>>(HG2, ln_fg_g, ln_fg_b, HGnb);
    mgemm_kernel<false,true,true,false,false><<<dim3(125, 8), 256, 0, stream>>>(
        HGnb, fgW1b, fg_b1, nullptr, G2, NG, DFF, DD);
    mgemm_kernel<true,true,false,true,false><<<dim3(125, 2), 256, 0, stream>>>(
        G2, fgW2b, fg_b2, HG2, out_HG3, NG, DD, DFF);
}

// Round 11
// 658.391 us; speedup vs baseline: 3.2237x; 1.1101x over previous
//
#include <hip/hip_runtime.h>
#include <hip/hip_bf16.h>

#define NTF 600
#define NG  8000
#define DD  256
#define HH  4
#define DKK 32
#define DVV 64
#define DFF 1024

typedef __attribute__((ext_vector_type(8))) short frag_ab;   // 8 bf16
typedef __attribute__((ext_vector_type(4))) float frag_cd;   // 4 f32

__device__ __forceinline__ unsigned short f2bu(float f) {
    __hip_bfloat16 h = __float2bfloat16(f);
    return __builtin_bit_cast(unsigned short, h);
}
__device__ __forceinline__ short f2bs(float f) { return (short)f2bu(f); }

// ---------------- f32 -> bf16 convert for z_seq/z_exp/z_txt ----------------
__global__ __launch_bounds__(256)
void cvt3_kernel(const float* __restrict__ a, const float* __restrict__ b, const float* __restrict__ c,
                 unsigned short* __restrict__ oa, unsigned short* __restrict__ ob,
                 unsigned short* __restrict__ oc, int n4) {
    for (int i = blockIdx.x * 256 + threadIdx.x; i < 3 * n4; i += gridDim.x * 256) {
        int sel = i / n4, j = i - sel * n4;
        const float* src = (sel == 0) ? a : (sel == 1) ? b : c;
        unsigned short* dst = (sel == 0) ? oa : (sel == 1) ? ob : oc;
        float4 v = ((const float4*)src)[j];
        ushort4 o = {f2bu(v.x), f2bu(v.y), f2bu(v.z), f2bu(v.w)};
        ((ushort4*)dst)[j] = o;
    }
}

// ---------------- weights f32 -> bf16 (13 tensors, blockIdx.y selects) ----------------
__global__ __launch_bounds__(256)
void cvt_w_kernel(const float* s0, const float* s1, const float* s2, const float* s3,
                  const float* s4, const float* s5, const float* s6, const float* s7,
                  const float* s8, const float* s9, const float* s10, const float* s11,
                  const float* s12, unsigned short* __restrict__ dst) {
    const int y = blockIdx.y;
    const float* src; int off, n;
    switch (y) {
        case 0:  src = s0;  off = 0;       n = 32768;  break;
        case 1:  src = s1;  off = 32768;   n = 32768;  break;
        case 2:  src = s2;  off = 65536;   n = 32768;  break;
        case 3:  src = s3;  off = 98304;   n = 32768;  break;
        case 4:  src = s4;  off = 131072;  n = 32768;  break;
        case 5:  src = s5;  off = 163840;  n = 32768;  break;
        case 6:  src = s6;  off = 196608;  n = 65536;  break;
        case 7:  src = s7;  off = 262144;  n = 65536;  break;
        case 8:  src = s8;  off = 327680;  n = 65536;  break;
        case 9:  src = s9;  off = 393216;  n = 262144; break;
        case 10: src = s10; off = 655360;  n = 262144; break;
        case 11: src = s11; off = 917504;  n = 262144; break;
        default: src = s12; off = 1179648; n = 262144; break;
    }
    const int n4 = n >> 2;
    for (int i = blockIdx.x * 256 + threadIdx.x; i < n4; i += gridDim.x * 256) {
        float4 v = ((const float4*)src)[i];
        ushort4 o = {f2bu(v.x), f2bu(v.y), f2bu(v.z), f2bu(v.w)};
        ((ushort4*)(dst + off))[i] = o;
    }
}

// ---------------- LayerNorm: f32 in, bf16 out ----------------
__global__ __launch_bounds__(64)
void ln_b_kernel(const float* __restrict__ x, const float* __restrict__ g,
                 const float* __restrict__ b, unsigned short* __restrict__ y) {
    int row = blockIdx.x;
    int tid = threadIdx.x;
    const float4* xp = (const float4*)(x + (size_t)row * DD);
    float4 v = xp[tid];
    float s = v.x + v.y + v.z + v.w;
    #pragma unroll
    for (int off = 32; off > 0; off >>= 1) s += __shfl_xor(s, off, 64);
    float mean = s * (1.f / 256.f);
    float dx = v.x - mean, dy = v.y - mean, dz = v.z - mean, dw = v.w - mean;
    float q = dx*dx + dy*dy + dz*dz + dw*dw;
    #pragma unroll
    for (int off = 32; off > 0; off >>= 1) q += __shfl_xor(q, off, 64);
    float inv = rsqrtf(q * (1.f / 256.f) + 1e-5f);
    float4 gg = ((const float4*)g)[tid];
    float4 bb = ((const float4*)b)[tid];
    ushort4 o = {f2bu(dx * inv * gg.x + bb.x), f2bu(dy * inv * gg.y + bb.y),
                 f2bu(dz * inv * gg.z + bb.z), f2bu(dw * inv * gg.w + bb.w)};
    ((ushort4*)(y + (size_t)row * DD))[tid] = o;
}

// ---------------- gather z[tf_idx] -> bf16 ----------------
__global__ __launch_bounds__(256)
void gather_b_kernel(const float* __restrict__ zs, const float* __restrict__ ze,
                     const float* __restrict__ zt, const int* __restrict__ idx,
                     unsigned short* __restrict__ os, unsigned short* __restrict__ oe,
                     unsigned short* __restrict__ ot) {
    int t = blockIdx.x, j = threadIdx.x;
    size_t src = (size_t)idx[t] * DD + j;
    size_t dst = (size_t)t * DD + j;
    os[dst] = f2bu(zs[src]);
    oe[dst] = f2bu(ze[src]);
    ot[dst] = f2bu(zt[src]);
}

// ---------------- MFMA GEMM: Y = act(X @ W^T + bias) (+res) ----------------
// X: [M,K] bf16 (or f32 if XF32), W: [N,K] bf16, res/bias f32, Y f32 or bf16.
// Block 256 thr = 4 waves (2x2); tile 64x128; K-step 32. Requires N%128==0, K%32==0.
template<bool XF32, bool BIAS, bool GELU, bool RES, bool OB16>
__device__ __forceinline__
void mgemm_core(const void* __restrict__ Xv, const unsigned short* __restrict__ W,
                const float* __restrict__ bias, const float* __restrict__ res,
                void* __restrict__ Yv, int M, int N, int K) {
    const int lane = threadIdx.x & 63, wv = threadIdx.x >> 6;
    const int wm = wv >> 1, wn = wv & 1;
    const int lr = lane & 15, lk = lane >> 4;
    const int m0 = blockIdx.x * 64, n0 = blockIdx.y * 128;
    frag_cd zz = {0.f, 0.f, 0.f, 0.f};
    frag_cd acc[2][4];
    #pragma unroll
    for (int mi = 0; mi < 2; ++mi)
        #pragma unroll
        for (int ni = 0; ni < 4; ++ni) acc[mi][ni] = zz;
    int arow[2], brow[4];
    #pragma unroll
    for (int mi = 0; mi < 2; ++mi) arow[mi] = min(m0 + wm * 32 + mi * 16 + lr, M - 1);
    #pragma unroll
    for (int ni = 0; ni < 4; ++ni) brow[ni] = n0 + wn * 64 + ni * 16 + lr;
    for (int k0 = 0; k0 < K; k0 += 32) {
        frag_ab af[2], bfr[4];
        #pragma unroll
        for (int mi = 0; mi < 2; ++mi) {
            if (XF32) {
                const float* xp = (const float*)Xv + (size_t)arow[mi] * K + k0 + lk * 8;
                float4 v0 = *(const float4*)xp;
                float4 v1 = *(const float4*)(xp + 4);
                frag_ab t;
                t[0] = f2bs(v0.x); t[1] = f2bs(v0.y); t[2] = f2bs(v0.z); t[3] = f2bs(v0.w);
                t[4] = f2bs(v1.x); t[5] = f2bs(v1.y); t[6] = f2bs(v1.z); t[7] = f2bs(v1.w);
                af[mi] = t;
            } else {
                af[mi] = *(const frag_ab*)((const unsigned short*)Xv + (size_t)arow[mi] * K + k0 + lk * 8);
            }
        }
        #pragma unroll
        for (int ni = 0; ni < 4; ++ni)
            bfr[ni] = *(const frag_ab*)(W + (size_t)brow[ni] * K + k0 + lk * 8);
        #pragma unroll
        for (int mi = 0; mi < 2; ++mi)
            #pragma unroll
            for (int ni = 0; ni < 4; ++ni)
                acc[mi][ni] = __builtin_amdgcn_mfma_f32_16x16x32_bf16(af[mi], bfr[ni], acc[mi][ni], 0, 0, 0);
    }
    #pragma unroll
    for (int ni = 0; ni < 4; ++ni) {
        const int n = brow[ni];
        const float bn = BIAS ? bias[n] : 0.f;
        #pragma unroll
        for (int mi = 0; mi < 2; ++mi) {
            #pragma unroll
            for (int r = 0; r < 4; ++r) {
                const int m = m0 + wm * 32 + mi * 16 + lk * 4 + r;
                if (m < M) {
                    float v = acc[mi][ni][r] + bn;
                    if (GELU) v = 0.5f * v * (1.f + erff(v * 0.70710678118654752f));
                    if (RES)  v += res[(size_t)m * N + n];
                    if (OB16) ((unsigned short*)Yv)[(size_t)m * N + n] = f2bu(v);
                    else      ((float*)Yv)[(size_t)m * N + n] = v;
                }
            }
        }
    }
}

template<bool XF32, bool BIAS, bool GELU, bool RES, bool OB16>
__global__ __launch_bounds__(256)
void mgemm_kernel(const void* __restrict__ X, const unsigned short* __restrict__ W,
                  const float* __restrict__ bias, const float* __restrict__ res,
                  void* __restrict__ Y, int M, int N, int K) {
    mgemm_core<XF32, BIAS, GELU, RES, OB16>(X, W, bias, res, Y, M, N, K);
}

// 3 problems batched via blockIdx.z (Q/K projections), bf16 out
__global__ __launch_bounds__(256)
void mgemm3_kernel(const unsigned short* X0, const unsigned short* W0, unsigned short* Y0,
                   const unsigned short* X1, const unsigned short* W1, unsigned short* Y1,
                   const unsigned short* X2, const unsigned short* W2, unsigned short* Y2,
                   int M, int N, int K) {
    const unsigned short* X = (blockIdx.z == 0) ? X0 : (blockIdx.z == 1) ? X1 : X2;
    const unsigned short* W = (blockIdx.z == 0) ? W0 : (blockIdx.z == 1) ? W1 : W2;
    unsigned short*       Y = (blockIdx.z == 0) ? Y0 : (blockIdx.z == 1) ? Y1 : Y2;
    mgemm_core<false, false, false, false, true>(X, W, nullptr, nullptr, Y, M, N, K);
}

// ---------------- scores + gate + u via MFMA; writes U, umean, alpha_mean ----------------
// Block 256 = 4 waves; wave w owns rows [t0+w*16, +16) x 64 g, ALL 4 heads (reduced in regs).
__global__ __launch_bounds__(256)
void scores_mfma(const unsigned short* __restrict__ Qse, const unsigned short* __restrict__ Qex,
                 const unsigned short* __restrict__ Qtx,
                 const unsigned short* __restrict__ Kse, const unsigned short* __restrict__ Kex,
                 const unsigned short* __restrict__ Ktx,
                 const float* __restrict__ gw, const float* __restrict__ gb,
                 float* __restrict__ U, float* __restrict__ umean, float* __restrict__ amean) {
    const int lane = threadIdx.x & 63, wv = threadIdx.x >> 6;
    const int lr = lane & 15, lk = lane >> 4;
    const int t0 = blockIdx.x * 64 + wv * 16;
    const int g0 = blockIdx.y * 64;
    const int tq = min(t0 + lr, NTF - 1);
    frag_cd zz = {0.f, 0.f, 0.f, 0.f};

    frag_ab qf[3][4];
    #pragma unroll
    for (int h = 0; h < HH; ++h) {
        qf[0][h] = *(const frag_ab*)(Qse + (size_t)tq * 128 + h * DKK + lk * 8);
        qf[1][h] = *(const frag_ab*)(Qex + (size_t)tq * 128 + h * DKK + lk * 8);
        qf[2][h] = *(const frag_ab*)(Qtx + (size_t)tq * 128 + h * DKK + lk * 8);
    }
    float gwr[HH][3][3], gbr[HH][3];
    #pragma unroll
    for (int h = 0; h < HH; ++h) {
        #pragma unroll
        for (int e = 0; e < 3; ++e)
            #pragma unroll
            for (int f = 0; f < 3; ++f) gwr[h][e][f] = gw[h * 9 + e * 3 + f];
        #pragma unroll
        for (int f = 0; f < 3; ++f) gbr[h][f] = gb[h * 3 + f];
    }
    const float sc = 0.17677669529663687f;  // 1/sqrt(32)

    #pragma unroll
    for (int gi = 0; gi < 4; ++gi) {
        const int gg = g0 + gi * 16;
        const int gk = gg + lr;
        float us[4] = {0.f, 0.f, 0.f, 0.f};
        float a0s[4] = {0.f, 0.f, 0.f, 0.f};
        float a1s[4] = {0.f, 0.f, 0.f, 0.f};
        float a2s[4] = {0.f, 0.f, 0.f, 0.f};
        #pragma unroll
        for (int h = 0; h < HH; ++h) {
            frag_ab kf0 = *(const frag_ab*)(Kse + (size_t)gk * 128 + h * DKK + lk * 8);
            frag_ab kf1 = *(const frag_ab*)(Kex + (size_t)gk * 128 + h * DKK + lk * 8);
            frag_ab kf2 = *(const frag_ab*)(Ktx + (size_t)gk * 128 + h * DKK + lk * 8);
            frag_cd s0 = __builtin_amdgcn_mfma_f32_16x16x32_bf16(qf[0][h], kf0, zz, 0, 0, 0);
            frag_cd s1 = __builtin_amdgcn_mfma_f32_16x16x32_bf16(qf[1][h], kf1, zz, 0, 0, 0);
            frag_cd s2 = __builtin_amdgcn_mfma_f32_16x16x32_bf16(qf[2][h], kf2, zz, 0, 0, 0);
            #pragma unroll
            for (int r = 0; r < 4; ++r) {
                const int t = t0 + lk * 4 + r;
                float e0 = s0[r] * sc, e1 = s1[r] * sc, e2 = s2[r] * sc;
                float lg0 = e0 * gwr[h][0][0] + e1 * gwr[h][1][0] + e2 * gwr[h][2][0] + gbr[h][0];
                float lg1 = e0 * gwr[h][0][1] + e1 * gwr[h][1][1] + e2 * gwr[h][2][1] + gbr[h][1];
                float lg2 = e0 * gwr[h][0][2] + e1 * gwr[h][1][2] + e2 * gwr[h][2][2] + gbr[h][2];
                float mx = fmaxf(lg0, fmaxf(lg1, lg2));
                float x0 = __expf(lg0 - mx), x1 = __expf(lg1 - mx), x2 = __expf(lg2 - mx);
                float inv = 1.f / (x0 + x1 + x2);
                float a0 = x0 * inv, a1 = x1 * inv, a2 = x2 * inv;
                float u = a0 * e0 + a1 * e1 + a2 * e2;
                if (t < NTF) U[((size_t)h * NTF + t) * NG + gg + lr] = u;
                us[r] += u; a0s[r] += a0; a1s[r] += a1; a2s[r] += a2;
            }
        }
        #pragma unroll
        for (int r = 0; r < 4; ++r) {
            const int t = t0 + lk * 4 + r;
            if (t < NTF) {
                size_t p = (size_t)t * NG + gg + lr;
                umean[p] = us[r] * 0.25f;
                amean[p * 3 + 0] = a0s[r] * 0.25f;
                amean[p * 3 + 1] = a1s[r] * 0.25f;
                amean[p * 3 + 2] = a2s[r] * 0.25f;
            }
        }
    }
}

// ---------------- row softmax over genes (in place, U -> A) fused with A.mean over h ----------------
__global__ __launch_bounds__(512)
void softmax_amean_kernel(float* __restrict__ U, float* __restrict__ Am) {
    __shared__ float sred[8];
    const int t = blockIdx.x, tid = threadIdx.x;
    const int w = tid >> 6;
    float am[16] = {};
    for (int h = 0; h < HH; ++h) {
        float* p = U + ((size_t)h * NTF + t) * NG;
        float v[16];
        float mx = -1e30f;
        #pragma unroll
        for (int i = 0; i < 16; ++i) {
            int j = i * 512 + tid;
            v[i] = (j < NG) ? p[j] : -1e30f;
            mx = fmaxf(mx, v[i]);
        }
        #pragma unroll
        for (int off = 32; off > 0; off >>= 1) mx = fmaxf(mx, __shfl_xor(mx, off, 64));
        __syncthreads();
        if ((tid & 63) == 0) sred[w] = mx;
        __syncthreads();
        mx = sred[0];
        #pragma unroll
        for (int k = 1; k < 8; ++k) mx = fmaxf(mx, sred[k]);
        float sum = 0.f;
        #pragma unroll
        for (int i = 0; i < 16; ++i) {
            int j = i * 512 + tid;
            v[i] = (j < NG) ? __expf(v[i] - mx) : 0.f;
            sum += v[i];
        }
        #pragma unroll
        for (int off = 32; off > 0; off >>= 1) sum += __shfl_xor(sum, off, 64);
        __syncthreads();
        if ((tid & 63) == 0) sred[w] = sum;
        __syncthreads();
        float tot = 0.f;
        #pragma unroll
        for (int k = 0; k < 8; ++k) tot += sred[k];
        float inv = 1.f / tot;
        #pragma unroll
        for (int i = 0; i < 16; ++i) {
            int j = i * 512 + tid;
            float a = v[i] * inv;
            if (j < NG) p[j] = a;
            am[i] += a;
        }
    }
    #pragma unroll
    for (int i = 0; i < 16; ++i) {
        int j = i * 512 + tid;
        if (j < NG) Am[(size_t)t * NG + j] = am[i] * 0.25f;
    }
}

// ---------------- VG -> VGT: [8000][256] f32 slice -> [h][64][8000] bf16 ----------------
__global__ __launch_bounds__(256)
void vgt_kernel(const float* __restrict__ VG, unsigned short* __restrict__ VGT) {
    __shared__ float tile[64][65];
    const int g0 = blockIdx.x * 64;     // 125 blocks, exact
    const int h  = blockIdx.y;
    const int tid = threadIdx.x;
    const int c = tid & 63, r0 = (tid >> 6) * 16;
    #pragma unroll
    for (int i = 0; i < 16; ++i)
        tile[r0 + i][c] = VG[(size_t)(g0 + r0 + i) * DD + h * DVV + c];
    __syncthreads();
    #pragma unroll
    for (int i = 0; i < 16; ++i)
        VGT[(size_t)(h * 64 + r0 + i) * NG + g0 + c] = f2bu(tile[c][r0 + i]);
}

// ---------------- out_tf = einsum('htg,ghv->thv') via MFMA, split-K, atomic epilogue ----------------
// grid (10 t-tiles, 4 h, 16 k-chunks of 512); 256 thr = 4 waves, each 16 t x 64 v.
// A f32 converted to bf16 fragments in-register; VGT bf16 [h][64][8000].
__global__ __launch_bounds__(256)
void attn_tf_mfma(const float* __restrict__ A, const unsigned short* __restrict__ VGT,
                  float* __restrict__ AT) {
    const int lane = threadIdx.x & 63, wv = threadIdx.x >> 6;
    const int lr = lane & 15, lk = lane >> 4;
    const int t0 = blockIdx.x * 64 + wv * 16;
    const int h  = blockIdx.y;
    const int kbase = blockIdx.z * 512;
    const float* arow = A + (size_t)h * NTF * NG + (size_t)min(t0 + lr, NTF - 1) * NG;
    const unsigned short* Vh = VGT + (size_t)h * 64 * NG;
    frag_cd zz = {0.f, 0.f, 0.f, 0.f};
    frag_cd acc[4] = {zz, zz, zz, zz};
    const int kend = min(kbase + 512, NG);   // 16*512=8192 > 8000; 8000 % 32 == 0 so step-level clamp is exact
    for (int k0 = kbase; k0 < kend; k0 += 32) {
        const float* ap = arow + k0 + lk * 8;
        float4 v0 = *(const float4*)ap;
        float4 v1 = *(const float4*)(ap + 4);
        frag_ab af;
        af[0] = f2bs(v0.x); af[1] = f2bs(v0.y); af[2] = f2bs(v0.z); af[3] = f2bs(v0.w);
        af[4] = f2bs(v1.x); af[5] = f2bs(v1.y); af[6] = f2bs(v1.z); af[7] = f2bs(v1.w);
        #pragma unroll
        for (int ni = 0; ni < 4; ++ni) {
            frag_ab bf = *(const frag_ab*)(Vh + (size_t)(ni * 16 + lr) * NG + k0 + lk * 8);
            acc[ni] = __builtin_amdgcn_mfma_f32_16x16x32_bf16(af, bf, acc[ni], 0, 0, 0);
        }
    }
    #pragma unroll
    for (int ni = 0; ni < 4; ++ni) {
        const int v = ni * 16 + lr;
        #pragma unroll
        for (int r = 0; r < 4; ++r) {
            const int t = t0 + lk * 4 + r;
            if (t < NTF)
                atomicAdd(&AT[(size_t)t * DD + h * DVV + v], acc[ni][r]);
        }
    }
}

// ---------------- out_g = einsum('htg,thv->ghv'), bf16 output ----------------
__global__ __launch_bounds__(256)
void attn_g_kernel(const float* __restrict__ A, const float* __restrict__ VTF,
                   unsigned short* __restrict__ ATb) {
    __shared__ float As[16][68];
    __shared__ float Vs[16][68];
    const int tid = threadIdx.x;
    const int tx = tid & 15, ty = tid >> 4;
    const int g0 = blockIdx.x * 64;
    const int h  = blockIdx.y;
    const float* Ah = A + (size_t)h * NTF * NG;
    float acc[4][4] = {};
    for (int t0 = 0; t0 < NTF; t0 += 16) {
        __syncthreads();
        #pragma unroll
        for (int j = 0; j < 4; ++j) {
            int idx = j * 256 + tid;
            int m = idx & 63, k = idx >> 6;
            int t = t0 + k;
            As[k][m] = (t < NTF) ? Ah[(size_t)t * NG + g0 + m] : 0.f;
            Vs[k][m] = (t < NTF) ? VTF[(size_t)t * DD + h * DVV + m] : 0.f;
        }
        __syncthreads();
        #pragma unroll
        for (int k = 0; k < 16; ++k) {
            float4 a4 = *(const float4*)&As[k][ty * 4];
            float4 b4 = *(const float4*)&Vs[k][tx * 4];
            float a[4] = {a4.x, a4.y, a4.z, a4.w};
            float b[4] = {b4.x, b4.y, b4.z, b4.w};
            #pragma unroll
            for (int i = 0; i < 4; ++i)
                #pragma unroll
                for (int j = 0; j < 4; ++j)
                    acc[i][j] += a[i] * b[j];
        }
    }
    #pragma unroll
    for (int i = 0; i < 4; ++i) {
        ushort4 o = {f2bu(acc[i][0]), f2bu(acc[i][1]), f2bu(acc[i][2]), f2bu(acc[i][3])};
        *(ushort4*)&ATb[(size_t)(g0 + ty * 4 + i) * DD + h * DVV + tx * 4] = o;
    }
}

// ---------------- f32 SIMT GEMM (kept only for WOTF: X=ATtf f32 from atomics) ----------------
template<bool RES>
__global__ __launch_bounds__(256)
void gemm_xwt(const float* __restrict__ X, const float* __restrict__ W,
              const float* __restrict__ res, float* __restrict__ Y, int M, int N, int K) {
    __shared__ float Xs[16][132];
    __shared__ float Ws[16][132];
    const int tid = threadIdx.x;
    const int bm = blockIdx.x * 128, bn = blockIdx.y * 128;
    const int tx = tid & 15, ty = tid >> 4;
    float acc[8][8] = {};
    for (int k0 = 0; k0 < K; k0 += 16) {
        __syncthreads();
        #pragma unroll
        for (int j = 0; j < 8; ++j) {
            int idx = j * 256 + tid;
            int k = idx & 15, m = idx >> 4;
            Xs[k][m] = (bm + m < M) ? X[(size_t)(bm + m) * K + k0 + k] : 0.f;
            Ws[k][m] = W[(size_t)(bn + m) * K + k0 + k];
        }
        __syncthreads();
        #pragma unroll
        for (int k = 0; k < 16; ++k) {
            float4 a0 = *(const float4*)&Xs[k][ty * 8];
            float4 a1 = *(const float4*)&Xs[k][ty * 8 + 4];
            float4 b0 = *(const float4*)&Ws[k][tx * 8];
            float4 b1 = *(const float4*)&Ws[k][tx * 8 + 4];
            float a[8] = {a0.x,a0.y,a0.z,a0.w,a1.x,a1.y,a1.z,a1.w};
            float b[8] = {b0.x,b0.y,b0.z,b0.w,b1.x,b1.y,b1.z,b1.w};
            #pragma unroll
            for (int i = 0; i < 8; ++i)
                #pragma unroll
                for (int j = 0; j < 8; ++j)
                    acc[i][j] += a[i] * b[j];
        }
    }
    #pragma unroll
    for (int i = 0; i < 8; ++i) {
        int m = bm + ty * 8 + i;
        if (m >= M) continue;
        #pragma unroll
        for (int j = 0; j < 8; ++j) {
            int n = bn + tx * 8 + j;
            float v = acc[i][j];
            if (RES) v += res[(size_t)m * N + n];
            Y[(size_t)m * N + n] = v;
        }
    }
}

extern "C" void kernel_launch(void* const* d_in, const int* in_sizes, int n_in,
                              void* d_out, int out_size, void* d_ws, size_t ws_size,
                              hipStream_t stream) {
    (void)in_sizes; (void)n_in; (void)out_size; (void)ws_size;
    const float* H_TF   = (const float*)d_in[0];
    const float* H_G    = (const float*)d_in[1];
    const float* z_exp  = (const float*)d_in[2];
    const float* z_seq  = (const float*)d_in[3];
    const float* z_txt  = (const float*)d_in[4];
    const int*   tf_idx = (const int*)d_in[5];
    const float* WQ_seq = (const float*)d_in[6];
    const float* WK_seq = (const float*)d_in[7];
    const float* WQ_exp = (const float*)d_in[8];
    const float* WK_exp = (const float*)d_in[9];
    const float* WQ_txt = (const float*)d_in[10];
    const float* WK_txt = (const float*)d_in[11];
    const float* gate_w = (const float*)d_in[12];
    const float* gate_b = (const float*)d_in[13];
    const float* WVG    = (const float*)d_in[14];
    const float* WVTF   = (const float*)d_in[15];
    const float* WOTF   = (const float*)d_in[16];
    const float* WOG    = (const float*)d_in[17];
    const float* ln_atf_g = (const float*)d_in[18];
    const float* ln_atf_b = (const float*)d_in[19];
    const float* ln_ag_g  = (const float*)d_in[20];
    const float* ln_ag_b  = (const float*)d_in[21];
    const float* ln_ftf_g = (const float*)d_in[22];
    const float* ln_ftf_b = (const float*)d_in[23];
    const float* ln_fg_g  = (const float*)d_in[24];
    const float* ln_fg_b  = (const float*)d_in[25];
    const float* ftf_W1 = (const float*)d_in[26];
    const float* ftf_b1 = (const float*)d_in[27];
    const float* ftf_W2 = (const float*)d_in[28];
    const float* ftf_b2 = (const float*)d_in[29];
    const float* fg_W1  = (const float*)d_in[30];
    const float* fg_b1  = (const float*)d_in[31];
    const float* fg_W2  = (const float*)d_in[32];
    const float* fg_b2  = (const float*)d_in[33];

    float* out = (float*)d_out;
    float* out_HTF3  = out;                    // 600*256
    float* out_HG3   = out + 153600;           // 8000*256
    float* out_Amean = out + 2201600;          // 600*8000
    float* out_umean = out + 7001600;          // 600*8000
    float* out_amean = out + 11801600;         // 600*8000*3

    // ---- workspace layout (f32 units) ----
    float* ws = (float*)d_ws;
    float* U    = ws;                          // 19,200,000 f32  (A in place after softmax)
    float* VG   = ws + 19200000;               //  2,048,000
    float* VTF  = VG + 2048000;                //    153,600
    float* ATtf = VTF + 153600;                //    153,600
    float* HTF2 = ATtf + 153600;               //    153,600
    float* HG2  = HTF2 + 153600;               //  2,048,000  -> f32 end 23,756,800
    // f32 aliases inside U (A dead after attn kernels):
    float* G2 = U;                             // 8,192,000 (fg gelu out)
    float* G1 = U + 8192000;                   //   614,400 (ftf gelu out)
    // bf16 region (dedicated)
    unsigned short* bws   = (unsigned short*)(ws + 23756800);
    unsigned short* Kb_se = bws;               // 1,024,000 each
    unsigned short* Kb_ex = bws + 1024000;
    unsigned short* Kb_tx = bws + 2048000;
    unsigned short* Qb_se = bws + 3072000;     // 76,800 each
    unsigned short* Qb_ex = bws + 3148800;
    unsigned short* Qb_tx = bws + 3225600;
    unsigned short* Wb    = bws + 3302400;     // 1,441,792
    unsigned short* HTFnb = bws + 4744192;     // 153,600  (attn LN, reused for FFN LN)
    unsigned short* HGnb  = bws + 4897792;     // 2,048,000
    unsigned short* VGT   = bws + 6945792;     // 2,048,000 bf16 [4][64][8000] -> bf16 end 8,993,792 (~113 MB total; R1 used 127 MB OK)
    // bf16 aliases inside U (dead before scores writes U):
    unsigned short* zb_se = (unsigned short*)U;             // 2,048,000 each
    unsigned short* zb_ex = zb_se + 2048000;
    unsigned short* zb_tx = zb_se + 4096000;
    unsigned short* ztb_se = zb_se + 6144000;               // 153,600 each
    unsigned short* ztb_ex = ztb_se + 153600;
    unsigned short* ztb_tx = ztb_se + 307200;
    // bf16 alias inside VG (dead after attn_tf):
    unsigned short* ATgb = (unsigned short*)VG;             // 2,048,000

    // weight bf16 offsets inside Wb (order matches cvt_w_kernel)
    unsigned short* WQse_b = Wb + 0;
    unsigned short* WQex_b = Wb + 32768;
    unsigned short* WQtx_b = Wb + 65536;
    unsigned short* WKse_b = Wb + 98304;
    unsigned short* WKex_b = Wb + 131072;
    unsigned short* WKtx_b = Wb + 163840;
    unsigned short* WVGb   = Wb + 196608;
    unsigned short* WVTFb  = Wb + 262144;
    unsigned short* WOGb   = Wb + 327680;
    unsigned short* ftfW1b = Wb + 393216;
    unsigned short* ftfW2b = Wb + 655360;
    unsigned short* fgW1b  = Wb + 917504;
    unsigned short* fgW2b  = Wb + 1179648;

    // 0) converts
    cvt3_kernel<<<750, 256, 0, stream>>>(z_seq, z_exp, z_txt, zb_se, zb_ex, zb_tx, 512000);
    cvt_w_kernel<<<dim3(64, 13), 256, 0, stream>>>(
        WQ_seq, WQ_exp, WQ_txt, WK_seq, WK_exp, WK_txt,
        WVG, WVTF, WOG, ftf_W1, ftf_W2, fg_W1, fg_W2, Wb);

    // 1) attention layernorms (bf16 out)
    ln_b_kernel<<<NTF, 64, 0, stream>>>(H_TF, ln_atf_g, ln_atf_b, HTFnb);
    ln_b_kernel<<<NG,  64, 0, stream>>>(H_G,  ln_ag_g,  ln_ag_b,  HGnb);

    // 2) gather z[tf_idx] (bf16 out)
    gather_b_kernel<<<NTF, 256, 0, stream>>>(z_seq, z_exp, z_txt, tf_idx, ztb_se, ztb_ex, ztb_tx);

    // 3) projections (MFMA)
    mgemm3_kernel<<<dim3(10, 1, 3), 256, 0, stream>>>(ztb_se, WQse_b, Qb_se,
                                                      ztb_ex, WQex_b, Qb_ex,
                                                      ztb_tx, WQtx_b, Qb_tx, NTF, 128, DD);
    mgemm3_kernel<<<dim3(125, 1, 3), 256, 0, stream>>>(zb_se, WKse_b, Kb_se,
                                                       zb_ex, WKex_b, Kb_ex,
                                                       zb_tx, WKtx_b, Kb_tx, NG, 128, DD);
    mgemm_kernel<false,false,false,false,false><<<dim3(125, 2), 256, 0, stream>>>(
        HGnb, WVGb, nullptr, nullptr, VG, NG, DD, DD);
    mgemm_kernel<false,false,false,false,false><<<dim3(10, 2), 256, 0, stream>>>(
        HTFnb, WVTFb, nullptr, nullptr, VTF, NTF, DD, DD);

    // 3b) VG -> VGT bf16 (for MFMA attn_tf)
    vgt_kernel<<<dim3(125, HH), 256, 0, stream>>>(VG, VGT);

    // 4) scores + gate + u (+ umean, alpha_mean) — MFMA
    scores_mfma<<<dim3(10, 125), 256, 0, stream>>>(
        Qb_se, Qb_ex, Qb_tx, Kb_se, Kb_ex, Kb_tx, gate_w, gate_b, U, out_umean, out_amean);

    // 5) softmax over genes (in place) fused with A.mean over heads
    softmax_amean_kernel<<<NTF, 512, 0, stream>>>(U, out_Amean);

    // 6) attention contractions
    hipMemsetAsync(ATtf, 0, (size_t)NTF * DD * sizeof(float), stream);
    attn_tf_mfma<<<dim3(10, HH, 16), 256, 0, stream>>>(U, VGT, ATtf);
    attn_g_kernel<<<dim3(NG / 64, HH), 256, 0, stream>>>(U, VTF, ATgb);

    // 7) output projections + residual
    gemm_xwt<true><<<dim3(5, 2), 256, 0, stream>>>(ATtf, WOTF, H_TF, HTF2, NTF, DD, DD);
    mgemm_kernel<false,false,false,true,false><<<dim3(125, 2), 256, 0, stream>>>(
        ATgb, WOGb, nullptr, H_G, HG2, NG, DD, DD);

    // 8) FFN (TF)
    ln_b_kernel<<<NTF, 64, 0, stream>>>(HTF2, ln_ftf_g, ln_ftf_b, HTFnb);
    mgemm_kernel<false,true,true,false,false><<<dim3(10, 8), 256, 0, stream>>>(
        HTFnb, ftfW1b, ftf_b1, nullptr, G1, NTF, DFF, DD);
    mgemm_kernel<true,true,false,true,false><<<dim3(10, 2), 256, 0, stream>>>(
        G1, ftfW2b, ftf_b2, HTF2, out_HTF3, NTF, DD, DFF);

    // 9) FFN (genes)
    ln_b_kernel<<<NG, 64, 0, stream>>>(HG2, ln_fg_g, ln_fg_b, HGnb);
    mgemm_kernel<false,true,true,false,false><<<dim3(125, 8), 256, 0, stream>>>(
        HGnb, fgW1b, fg_b1, nullptr, G2, NG, DFF, DD);
    mgemm_kernel<true,true,false,true,false><<<dim3(125, 2), 256, 0, stream>>>(
        G2, fgW2b, fg_b2, HG2, out_HG3, NG, DD, DFF);
}